// Round 1
// baseline (100.386 us; speedup 1.0000x reference)
//
#include <hip/hip_runtime.h>
#include <math.h>

// LAPACK >= 3.10 slartg convention (c >= 0). Flip to 0 to emulate <= 3.9.
#define NEW_SLARTG 1

// =============================================================================
// LAPACK sgesdd emulation for 3x3 (f32), faithful sign conventions.
// =============================================================================

__device__ __forceinline__ void slartg_f(float f, float g, float& c, float& s, float& r) {
#if NEW_SLARTG
  if (g == 0.0f) { c = 1.0f; s = 0.0f; r = f; }
  else if (f == 0.0f) { c = 0.0f; s = copysignf(1.0f, g); r = fabsf(g); }
  else {
    float d = sqrtf(f*f + g*g);
    c = fabsf(f) / d;
    r = copysignf(d, f);
    s = g / r;
  }
#else
  if (g == 0.0f) { c = 1.0f; s = 0.0f; r = f; }
  else if (f == 0.0f) { c = 0.0f; s = 1.0f; r = g; }
  else {
    float d = sqrtf(f*f + g*g);
    c = f / d; s = g / d; r = d;
    if (fabsf(f) > fabsf(g) && c < 0.0f) { c = -c; s = -s; r = -r; }
  }
#endif
}

__device__ __forceinline__ void slas2_f(float f, float g, float h, float& ssmin, float& ssmax) {
  float fa = fabsf(f), ga = fabsf(g), ha = fabsf(h);
  float fhmn = fminf(fa, ha), fhmx = fmaxf(fa, ha);
  if (fhmn == 0.0f) {
    ssmin = 0.0f;
    if (fhmx == 0.0f) ssmax = ga;
    else {
      float mn = fminf(fhmx, ga), mx = fmaxf(fhmx, ga);
      float qq = mn / mx;
      ssmax = mx * sqrtf(1.0f + qq*qq);
    }
  } else {
    if (ga < fhmx) {
      float as_ = 1.0f + fhmn/fhmx;
      float at_ = (fhmx - fhmn)/fhmx;
      float au_ = ga/fhmx; au_ = au_*au_;
      float c = 2.0f/(sqrtf(as_*as_ + au_) + sqrtf(at_*at_ + au_));
      ssmin = fhmn*c;
      ssmax = fhmx/c;
    } else {
      float au_ = fhmx/ga;
      if (au_ == 0.0f) {
        ssmin = (fhmn*fhmx)/ga;
        ssmax = ga;
      } else {
        float as_ = 1.0f + fhmn/fhmx;
        float at_ = (fhmx - fhmn)/fhmx;
        float t1 = as_*au_, t2 = at_*au_;
        float c = 1.0f/(sqrtf(1.0f + t1*t1) + sqrtf(1.0f + t2*t2));
        ssmin = (fhmn*c)*au_;
        ssmin = ssmin + ssmin;
        ssmax = ga/(c + c);
      }
    }
  }
}

__device__ void slasv2_f(float f, float g, float h,
                         float& ssmin, float& ssmax,
                         float& snr, float& csr, float& snl, float& csl) {
  const float eps = 5.9604645e-08f;
  float ft = f, fa = fabsf(f), ht = h, ha = fabsf(h);
  int pmax = 1;
  bool swap_ = (ha > fa);
  if (swap_) {
    pmax = 3;
    float tq = ft; ft = ht; ht = tq;
    tq = fa; fa = ha; ha = tq;
  }
  float gt = g, ga = fabsf(g);
  float clt = 0.f, crt = 0.f, slt = 0.f, srt = 0.f;
  if (ga == 0.0f) {
    ssmin = ha; ssmax = fa;
    clt = 1.0f; crt = 1.0f; slt = 0.0f; srt = 0.0f;
  } else {
    bool gasmal = true;
    if (ga > fa) {
      pmax = 2;
      if ((fa/ga) < eps) {
        gasmal = false;
        ssmax = ga;
        ssmin = (ha > 1.0f) ? (fa/(ga/ha)) : ((fa/ga)*ha);
        clt = 1.0f; slt = ht/gt; srt = 1.0f; crt = ft/gt;
      }
    }
    if (gasmal) {
      float dd = fa - ha;
      float l = (dd == fa) ? 1.0f : (dd/fa);
      float mr = gt/ft;                 // M
      float t = 2.0f - l;
      float mm2 = mr*mr, tt = t*t;
      float s_ = sqrtf(tt + mm2);
      float r_ = (l == 0.0f) ? fabsf(mr) : sqrtf(l*l + mm2);
      float a_ = 0.5f*(s_ + r_);
      ssmin = ha/a_;
      ssmax = fa*a_;
      if (mm2 == 0.0f) {
        if (l == 0.0f) t = copysignf(2.0f, ft)*copysignf(1.0f, gt);
        else t = gt/copysignf(dd, ft) + mr/t;
      } else {
        t = (mr/(s_ + t) + mr/(r_ + l))*(1.0f + a_);
      }
      float l2 = sqrtf(t*t + 4.0f);
      crt = 2.0f/l2;
      srt = t/l2;
      clt = (crt + srt*mr)/a_;
      slt = (ht/ft)*srt/a_;
    }
  }
  if (swap_) { csl = srt; snl = crt; csr = slt; snr = clt; }
  else       { csl = clt; snl = slt; csr = crt; snr = srt; }
  float tsign = 0.f;
  if (pmax == 1) tsign = copysignf(1.0f, csr)*copysignf(1.0f, csl)*copysignf(1.0f, f);
  if (pmax == 2) tsign = copysignf(1.0f, snr)*copysignf(1.0f, csl)*copysignf(1.0f, g);
  if (pmax == 3) tsign = copysignf(1.0f, snr)*copysignf(1.0f, snl)*copysignf(1.0f, h);
  ssmax = copysignf(ssmax, tsign);
  ssmin = copysignf(ssmin, tsign*copysignf(1.0f, f)*copysignf(1.0f, h));
}

__device__ __forceinline__ void rot_rows3(float mt[3][3], int r1, int r2, float c, float s) {
#pragma unroll
  for (int k = 0; k < 3; ++k) {
    float x = mt[r1][k], y = mt[r2][k];
    mt[r1][k] = c*x + s*y;
    mt[r2][k] = c*y - s*x;
  }
}
__device__ __forceinline__ void rot_cols3(float mt[3][3], int c1_, int c2_, float c, float s) {
#pragma unroll
  for (int k = 0; k < 3; ++k) {
    float x = mt[k][c1_], y = mt[k][c2_];
    mt[k][c1_] = c*x + s*y;
    mt[k][c2_] = c*y - s*x;
  }
}

#define D_(i) d[(i)-1]
#define E_(i) e[(i)-1]

// SBDSQR for n=3 upper bidiagonal; u, vt start as identity; accumulates rotations.
__device__ void sbdsqr3(float* d, float* e, float u[3][3], float vt[3][3]) {
  const float eps  = 5.9604645e-08f;
  const float unfl = 1.17549435e-38f;
  const float tol  = 10.0f*eps;           // tolmul = max(10,min(100,eps^-1/8=8)) = 10

  float sminoa = fabsf(d[0]);
  if (sminoa != 0.0f) {
    float mu = sminoa;
    mu = fabsf(d[1])*(mu/(mu + fabsf(e[0])));
    sminoa = fminf(sminoa, mu);
    if (sminoa != 0.0f) {
      mu = fabsf(d[2])*(mu/(mu + fabsf(e[1])));
      sminoa = fminf(sminoa, mu);
    }
  }
  sminoa = sminoa / sqrtf(3.0f);
  float thresh = fmaxf(tol*sminoa, 54.0f*unfl);   // maxitr*n*n*unfl = 6*9*unfl

  int m = 3, oldll = -1, oldm = -1, idir = 0;
  int guard = 0;
  while (m > 1 && ++guard < 200) {
    // ---- find diagonal block ----
    float smax = fabsf(D_(m));
    int ll = 1; bool split = false;
    for (int lll = 1; lll <= m-1; ++lll) {
      int l2 = m - lll;
      float abss = fabsf(D_(l2)), abse = fabsf(E_(l2));
      if (abse <= thresh) { ll = l2; split = true; break; }
      smax = fmaxf(smax, fmaxf(abss, abse));
    }
    if (split) {
      E_(ll) = 0.0f;
      if (ll == m-1) { m = m - 1; continue; }
      ll = ll + 1;
    } else ll = 1;

    if (ll == m-1) {
      // ---- 2x2 block: slasv2 ----
      float sigmn, sigmx, sinr, cosr, sinl, cosl;
      slasv2_f(D_(m-1), E_(m-1), D_(m), sigmn, sigmx, sinr, cosr, sinl, cosl);
      D_(m-1) = sigmx; D_(m) = sigmn; E_(m-1) = 0.0f;
      rot_rows3(vt, m-2, m-1, cosr, sinr);
      rot_cols3(u,  m-2, m-1, cosl, sinl);
      m -= 2; continue;
    }

    if (ll > oldm || m < oldll)
      idir = (fabsf(D_(ll)) >= fabsf(D_(m))) ? 1 : 2;

    // ---- convergence tests ----
    float sminl = 0.0f;
    bool deflated = false;
    if (idir == 1) {
      if (fabsf(E_(m-1)) <= tol*fabsf(D_(m))) { E_(m-1) = 0.0f; continue; }
      float mu = fabsf(D_(ll)); sminl = mu;
      for (int lll = ll; lll <= m-1; ++lll) {
        if (fabsf(E_(lll)) <= tol*mu) { E_(lll) = 0.0f; deflated = true; break; }
        mu = fabsf(D_(lll+1))*(mu/(mu + fabsf(E_(lll))));
        sminl = fminf(sminl, mu);
      }
    } else {
      if (fabsf(E_(ll)) <= tol*fabsf(D_(ll))) { E_(ll) = 0.0f; continue; }
      float mu = fabsf(D_(m)); sminl = mu;
      for (int lll = m-1; lll >= ll; --lll) {
        if (fabsf(E_(lll)) <= tol*mu) { E_(lll) = 0.0f; deflated = true; break; }
        mu = fabsf(D_(lll))*(mu/(mu + fabsf(E_(lll))));
        sminl = fminf(sminl, mu);
      }
    }
    if (deflated) continue;
    oldll = ll; oldm = m;

    // ---- shift ----
    float shift = 0.0f, rdum;
    if (!(3.0f*tol*(sminl/smax) <= fmaxf(eps, 0.01f*tol))) {
      float sll;
      if (idir == 1) { sll = fabsf(D_(ll)); slas2_f(D_(m-1), E_(m-1), D_(m), shift, rdum); }
      else           { sll = fabsf(D_(m));  slas2_f(D_(ll), E_(ll), D_(ll+1), shift, rdum); }
      if (sll > 0.0f) { float qq = shift/sll; if (qq*qq < eps) shift = 0.0f; }
    }

    // ---- QR sweep ----
    if (shift == 0.0f) {
      if (idir == 1) {
        float cs = 1.0f, oldcs = 1.0f, sn = 0.0f, oldsn = 0.0f, r;
        float c1[2], s1[2], c2[2], s2[2];
        int k = 0;
        for (int i = ll; i <= m-1; ++i, ++k) {
          float fin = D_(i)*cs;
          slartg_f(fin, E_(i), cs, sn, r);
          if (i > ll) E_(i-1) = oldsn*r;
          float f2 = oldcs*r, g2 = D_(i+1)*sn;
          slartg_f(f2, g2, oldcs, oldsn, D_(i));
          c1[k] = cs; s1[k] = sn; c2[k] = oldcs; s2[k] = oldsn;
        }
        float h = D_(m)*cs;
        D_(m) = h*oldcs;
        E_(m-1) = h*oldsn;
        k = 0;
        for (int i = ll; i <= m-1; ++i, ++k) rot_rows3(vt, i-1, i, c1[k], s1[k]);
        k = 0;
        for (int i = ll; i <= m-1; ++i, ++k) rot_cols3(u, i-1, i, c2[k], s2[k]);
        if (fabsf(E_(m-1)) <= thresh) E_(m-1) = 0.0f;
      } else {
        float cs = 1.0f, oldcs = 1.0f, sn = 0.0f, oldsn = 0.0f, r;
        float c1[2], s1[2], c2[2], s2[2];
        for (int i = m; i >= ll+1; --i) {
          float fin = D_(i)*cs;
          slartg_f(fin, E_(i-1), cs, sn, r);
          if (i < m) E_(i) = oldsn*r;
          float f2 = oldcs*r, g2 = D_(i-1)*sn;
          slartg_f(f2, g2, oldcs, oldsn, D_(i));
          int slot = i - ll;
          c1[slot-1] = cs; s1[slot-1] = -sn; c2[slot-1] = oldcs; s2[slot-1] = -oldsn;
        }
        float h = D_(ll)*cs;
        D_(ll) = h*oldcs;
        E_(ll) = h*oldsn;
        for (int j = m-ll; j >= 1; --j) rot_rows3(vt, ll+j-2, ll+j-1, c2[j-1], s2[j-1]);
        for (int j = m-ll; j >= 1; --j) rot_cols3(u,  ll+j-2, ll+j-1, c1[j-1], s1[j-1]);
        if (fabsf(E_(ll)) <= thresh) E_(ll) = 0.0f;
      }
    } else {
      if (idir == 1) {
        float f = (fabsf(D_(ll)) - shift)*(copysignf(1.0f, D_(ll)) + shift/D_(ll));
        float g = E_(ll);
        float cr, sr, cl, sl, r;
        float c1[2], s1[2], c2[2], s2[2];
        int k = 0;
        for (int i = ll; i <= m-1; ++i, ++k) {
          slartg_f(f, g, cr, sr, r);
          if (i > ll) E_(i-1) = r;
          f = cr*D_(i) + sr*E_(i);
          E_(i) = cr*E_(i) - sr*D_(i);
          g = sr*D_(i+1);
          D_(i+1) = cr*D_(i+1);
          slartg_f(f, g, cl, sl, r);
          D_(i) = r;
          f = cl*E_(i) + sl*D_(i+1);
          D_(i+1) = cl*D_(i+1) - sl*E_(i);
          if (i < m-1) { g = sl*E_(i+1); E_(i+1) = cl*E_(i+1); }
          c1[k] = cr; s1[k] = sr; c2[k] = cl; s2[k] = sl;
        }
        E_(m-1) = f;
        k = 0;
        for (int i = ll; i <= m-1; ++i, ++k) rot_rows3(vt, i-1, i, c1[k], s1[k]);
        k = 0;
        for (int i = ll; i <= m-1; ++i, ++k) rot_cols3(u, i-1, i, c2[k], s2[k]);
        if (fabsf(E_(m-1)) <= thresh) E_(m-1) = 0.0f;
      } else {
        float f = (fabsf(D_(m)) - shift)*(copysignf(1.0f, D_(m)) + shift/D_(m));
        float g = E_(m-1);
        float cr, sr, cl, sl, r;
        float c1[2], s1[2], c2[2], s2[2];
        for (int i = m; i >= ll+1; --i) {
          slartg_f(f, g, cr, sr, r);
          if (i < m) E_(i) = r;
          f = cr*D_(i) + sr*E_(i-1);
          E_(i-1) = cr*E_(i-1) - sr*D_(i);
          g = sr*D_(i-1);
          D_(i-1) = cr*D_(i-1);
          slartg_f(f, g, cl, sl, r);
          D_(i) = r;
          f = cl*E_(i-1) + sl*D_(i-1);
          D_(i-1) = cl*D_(i-1) - sl*E_(i-1);
          if (i > ll+1) { g = sl*E_(i-2); E_(i-2) = cl*E_(i-2); }
          int slot = i - ll;
          c1[slot-1] = cr; s1[slot-1] = -sr; c2[slot-1] = cl; s2[slot-1] = -sl;
        }
        E_(ll) = f;
        if (fabsf(E_(ll)) <= thresh) E_(ll) = 0.0f;
        for (int j = m-ll; j >= 1; --j) rot_rows3(vt, ll+j-2, ll+j-1, c2[j-1], s2[j-1]);
        for (int j = m-ll; j >= 1; --j) rot_cols3(u,  ll+j-2, ll+j-1, c1[j-1], s1[j-1]);
      }
    }
  }

  // ---- make singular values positive (negate VT rows) ----
  for (int i = 1; i <= 3; ++i) {
    if (D_(i) < 0.0f) {
      D_(i) = -D_(i);
#pragma unroll
      for (int k = 0; k < 3; ++k) vt[i-1][k] = -vt[i-1][k];
    }
  }
  // ---- sort decreasing (LAPACK selection sort with <=) ----
  for (int i = 1; i <= 2; ++i) {
    int isub = 1; float smn = D_(1);
    for (int j = 2; j <= 4-i; ++j) {
      if (D_(j) <= smn) { isub = j; smn = D_(j); }
    }
    if (isub != 4-i) {
      D_(isub) = D_(4-i); D_(4-i) = smn;
#pragma unroll
      for (int k = 0; k < 3; ++k) { float tq = vt[isub-1][k]; vt[isub-1][k] = vt[4-i-1][k]; vt[4-i-1][k] = tq; }
#pragma unroll
      for (int k = 0; k < 3; ++k) { float tq = u[k][isub-1]; u[k][isub-1] = u[k][4-i-1]; u[k][4-i-1] = tq; }
    }
  }
}

// Full sgesdd-path SVD of 3x3: A = U * diag(s) * VT (A row-major math convention)
__device__ void svd3_gesdd(const float Ain[3][3], float u[3][3], float vt[3][3]) {
  float a[3][3];
#pragma unroll
  for (int i = 0; i < 3; ++i)
#pragma unroll
    for (int j = 0; j < 3; ++j) a[i][j] = Ain[i][j];

  float d[3], e[2];
  float tq0 = 0.f, tq1 = 0.f, tp0 = 0.f;
  float v0a = 0.f, v0b = 0.f, v1a = 0.f, p0a = 0.f;

  // ---- SGEBD2 ----
  { // i=0 left reflector (column 0)
    float alpha = a[0][0];
    float xn = sqrtf(a[1][0]*a[1][0] + a[2][0]*a[2][0]);
    if (xn == 0.0f) { tq0 = 0.0f; d[0] = alpha; }
    else {
      float beta = -copysignf(sqrtf(alpha*alpha + xn*xn), alpha);
      tq0 = (beta - alpha)/beta;
      float sc = 1.0f/(alpha - beta);
      v0a = a[1][0]*sc; v0b = a[2][0]*sc;
      d[0] = beta;
    }
#pragma unroll
    for (int j = 1; j < 3; ++j) {
      float w = (a[0][j] + v0a*a[1][j] + v0b*a[2][j])*tq0;
      a[0][j] -= w; a[1][j] -= w*v0a; a[2][j] -= w*v0b;
    }
  }
  { // i=0 right reflector (row 0, cols 1..2)
    float alpha = a[0][1];
    float xn = fabsf(a[0][2]);
    if (xn == 0.0f) { tp0 = 0.0f; e[0] = alpha; }
    else {
      float beta = -copysignf(sqrtf(alpha*alpha + xn*xn), alpha);
      tp0 = (beta - alpha)/beta;
      p0a = a[0][2]/(alpha - beta);
      e[0] = beta;
    }
#pragma unroll
    for (int i = 1; i < 3; ++i) {
      float w = (a[i][1] + p0a*a[i][2])*tp0;
      a[i][1] -= w; a[i][2] -= w*p0a;
    }
  }
  { // i=1 left reflector (column 1, rows 1..2)
    float alpha = a[1][1];
    float xn = fabsf(a[2][1]);
    if (xn == 0.0f) { tq1 = 0.0f; d[1] = alpha; }
    else {
      float beta = -copysignf(sqrtf(alpha*alpha + xn*xn), alpha);
      tq1 = (beta - alpha)/beta;
      v1a = a[2][1]/(alpha - beta);
      d[1] = beta;
    }
    float w = (a[1][2] + v1a*a[2][2])*tq1;
    a[1][2] -= w; a[2][2] -= w*v1a;
  }
  e[1] = a[1][2];
  d[2] = a[2][2];

  // ---- SBDSQR on identity U_b, VT_b ----
  float ub[3][3] = {{1,0,0},{0,1,0},{0,0,1}};
  float vb[3][3] = {{1,0,0},{0,1,0},{0,0,1}};
  sbdsqr3(d, e, ub, vb);

  // ---- back-transform: U = H0*H1*Ub ; VT = Vb*G0 ----
#pragma unroll
  for (int j = 0; j < 3; ++j) {    // apply H1 (v = (0,1,v1a))
    float w = (ub[1][j] + v1a*ub[2][j])*tq1;
    ub[1][j] -= w; ub[2][j] -= w*v1a;
  }
#pragma unroll
  for (int j = 0; j < 3; ++j) {    // apply H0 (v = (1,v0a,v0b))
    float w = (ub[0][j] + v0a*ub[1][j] + v0b*ub[2][j])*tq0;
    ub[0][j] -= w; ub[1][j] -= w*v0a; ub[2][j] -= w*v0b;
  }
#pragma unroll
  for (int i = 0; i < 3; ++i) {    // VT = Vb * G0 (w = (0,1,p0a))
    float w = (vb[i][1] + p0a*vb[i][2])*tp0;
    vb[i][1] -= w; vb[i][2] -= w*p0a;
  }
#pragma unroll
  for (int i = 0; i < 3; ++i)
#pragma unroll
    for (int j = 0; j < 3; ++j) { u[i][j] = ub[i][j]; vt[i][j] = vb[i][j]; }
}

// =============================================================================
// Kernel 1: fused attention + per-(b,tile) partial reductions.
// grid = 256 blocks (16 batches x 16 n-tiles), 512 threads.
// thread -> (nl = tid&127) one n row; (q = tid>>7) one quarter of the m range.
// No max-subtraction needed: scores ~ N(0,1), exp() safe in f32, so partial
// (sum_e, sum_e*V) over m-chunks combine by plain addition.
// =============================================================================

__global__ __launch_bounds__(512)
void corr_kernel(const float* __restrict__ srcE, const float* __restrict__ tgtE,
                 const float* __restrict__ src, const float* __restrict__ tgt,
                 float* __restrict__ ws) {
  const int bid = blockIdx.x;
  const int b   = bid >> 4;
  const int nt  = bid & 15;
  const int tid = threadIdx.x;
  const int nl  = tid & 127;
  const int q   = tid >> 7;
  const int n   = nt*128 + nl;

  __shared__ __align__(16) float lds[4*128*20];     // per-quarter [128 m][16K+3V+1pad]
  __shared__ __align__(16) float parts[4][128][4];
  __shared__ float red[8][16];

  const float* sE = srcE + (size_t)b*16*2048;
  const float* kE = tgtE + (size_t)b*16*2048;
  const float* vE = tgt  + (size_t)b*3*2048;

  float qv[16];
#pragma unroll
  for (int dd = 0; dd < 16; ++dd) qv[dd] = sE[dd*2048 + n];

  float sum = 0.0f, a0 = 0.0f, a1 = 0.0f, a2 = 0.0f;

  for (int it = 0; it < 4; ++it) {
    __syncthreads();   // protect LDS reuse across iterations
    {
      const int m0 = q*512 + it*128;
      float* dst = &lds[q*128*20 + nl*20];
#pragma unroll
      for (int dd = 0; dd < 16; ++dd) dst[dd] = kE[dd*2048 + m0 + nl];
#pragma unroll
      for (int j = 0; j < 3; ++j) dst[16+j] = vE[j*2048 + m0 + nl];
    }
    __syncthreads();
    const float* rowbase = &lds[q*128*20];
#pragma unroll 4
    for (int mm = 0; mm < 128; ++mm) {
      const float4* rp = (const float4*)(rowbase + mm*20);
      float4 k0 = rp[0], k1 = rp[1], k2 = rp[2], k3 = rp[3], vv = rp[4];
      float s0 = qv[0]*k0.x + qv[1]*k0.y + qv[2]*k0.z + qv[3]*k0.w;
      float s1 = qv[4]*k1.x + qv[5]*k1.y + qv[6]*k1.z + qv[7]*k1.w;
      float s2 = qv[8]*k2.x + qv[9]*k2.y + qv[10]*k2.z + qv[11]*k2.w;
      float s3 = qv[12]*k3.x + qv[13]*k3.y + qv[14]*k3.z + qv[15]*k3.w;
      float ex = __expf(((s0+s1)+(s2+s3))*0.25f);
      sum += ex; a0 += ex*vv.x; a1 += ex*vv.y; a2 += ex*vv.z;
    }
  }

  *(float4*)&parts[q][nl][0] = make_float4(sum, a0, a1, a2);
  __syncthreads();

  float c0 = 0.f, c1 = 0.f, c2 = 0.f, s0v = 0.f, s1v = 0.f, s2v = 0.f;
  if (q == 0) {
    float4 p0 = *(const float4*)&parts[0][nl][0];
    float4 p1 = *(const float4*)&parts[1][nl][0];
    float4 p2 = *(const float4*)&parts[2][nl][0];
    float4 p3 = *(const float4*)&parts[3][nl][0];
    float S = (p0.x+p1.x) + (p2.x+p3.x);
    float inv = 1.0f/S;
    c0 = ((p0.y+p1.y)+(p2.y+p3.y))*inv;
    c1 = ((p0.z+p1.z)+(p2.z+p3.z))*inv;
    c2 = ((p0.w+p1.w)+(p2.w+p3.w))*inv;
    const float* sp = src + (size_t)b*3*2048;
    s0v = sp[n]; s1v = sp[2048+n]; s2v = sp[2*2048+n];
  }
  float vals[15] = { c0, c1, c2, s0v, s1v, s2v,
                     s0v*c0, s0v*c1, s0v*c2,
                     s1v*c0, s1v*c1, s1v*c2,
                     s2v*c0, s2v*c1, s2v*c2 };
#pragma unroll
  for (int k = 0; k < 15; ++k) {
    float v = vals[k];
    v += __shfl_xor(v, 1);  v += __shfl_xor(v, 2);  v += __shfl_xor(v, 4);
    v += __shfl_xor(v, 8);  v += __shfl_xor(v, 16); v += __shfl_xor(v, 32);
    vals[k] = v;
  }
  const int lane = tid & 63, wv = tid >> 6;
  if (lane == 0) {
#pragma unroll
    for (int k = 0; k < 15; ++k) red[wv][k] = vals[k];
  }
  __syncthreads();
  if (tid < 15) {
    float t = 0.0f;
#pragma unroll
    for (int w = 0; w < 8; ++w) t += red[w][tid];
    ws[bid*16 + tid] = t;
  }
}

// =============================================================================
// Kernel 2: per-batch final reduction, H, SVD (LAPACK-faithful), R & t.
// =============================================================================

__global__ void finalize_kernel(const float* __restrict__ ws, float* __restrict__ out) {
  const int b = threadIdx.x;
  if (b >= 16) return;

  float acc[15];
#pragma unroll
  for (int k = 0; k < 15; ++k) acc[k] = 0.0f;
  for (int t = 0; t < 16; ++t) {
    const float* p = ws + (size_t)(b*16 + t)*16;
#pragma unroll
    for (int k = 0; k < 15; ++k) acc[k] += p[k];
  }

  const float invN = 1.0f/2048.0f;
  float Sc[3] = {acc[0], acc[1], acc[2]};
  float Ss[3] = {acc[3], acc[4], acc[5]};
  float cm[3] = {Sc[0]*invN, Sc[1]*invN, Sc[2]*invN};
  float sm[3] = {Ss[0]*invN, Ss[1]*invN, Ss[2]*invN};

  float A[3][3];
#pragma unroll
  for (int i = 0; i < 3; ++i)
#pragma unroll
    for (int j = 0; j < 3; ++j)
      A[i][j] = acc[6 + i*3 + j] - Ss[i]*cm[j];

  float u[3][3], vt[3][3];
  svd3_gesdd(A, u, vt);

  // r = vh @ u^T  (r[i][k] = sum_j vt[i][j]*u[k][j])
  float R[3][3];
#pragma unroll
  for (int i = 0; i < 3; ++i)
#pragma unroll
    for (int k = 0; k < 3; ++k)
      R[i][k] = vt[i][0]*u[k][0] + vt[i][1]*u[k][1] + vt[i][2]*u[k][2];

  float det = R[0][0]*(R[1][1]*R[2][2] - R[1][2]*R[2][1])
            - R[0][1]*(R[1][0]*R[2][2] - R[1][2]*R[2][0])
            + R[0][2]*(R[1][0]*R[2][1] - R[1][1]*R[2][0]);

  if (det < 0.0f) {
#pragma unroll
    for (int i = 0; i < 3; ++i)
#pragma unroll
      for (int k = 0; k < 3; ++k)
        R[i][k] -= 2.0f*vt[i][2]*u[k][2];
  }

  float tv[3];
#pragma unroll
  for (int i = 0; i < 3; ++i)
    tv[i] = -(R[i][0]*sm[0] + R[i][1]*sm[1] + R[i][2]*sm[2]) + cm[i];

#pragma unroll
  for (int i = 0; i < 3; ++i)
#pragma unroll
    for (int j = 0; j < 3; ++j)
      out[b*9 + i*3 + j] = R[i][j];
#pragma unroll
  for (int i = 0; i < 3; ++i)
    out[144 + b*3 + i] = tv[i];
}

extern "C" void kernel_launch(void* const* d_in, const int* in_sizes, int n_in,
                              void* d_out, int out_size, void* d_ws, size_t ws_size,
                              hipStream_t stream) {
  const float* srcE = (const float*)d_in[0];
  const float* tgtE = (const float*)d_in[1];
  const float* src  = (const float*)d_in[2];
  const float* tgt  = (const float*)d_in[3];
  float* out = (float*)d_out;
  float* ws  = (float*)d_ws;

  hipLaunchKernelGGL(corr_kernel, dim3(256), dim3(512), 0, stream,
                     srcE, tgtE, src, tgt, ws);
  hipLaunchKernelGGL(finalize_kernel, dim3(1), dim3(64), 0, stream, ws, out);
}

// Round 2
// 62.807 us; speedup vs baseline: 1.5983x; 1.5983x over previous
//
#include <hip/hip_runtime.h>
#include <math.h>

// LAPACK >= 3.10 slartg convention (c >= 0). Flip to 0 to emulate <= 3.9.
#define NEW_SLARTG 1

typedef __attribute__((ext_vector_type(8))) short bf16x8;
typedef __attribute__((ext_vector_type(4))) float f32x4;

// =============================================================================
// LAPACK sgesdd emulation for 3x3 (f32), faithful sign conventions. (UNCHANGED)
// =============================================================================

__device__ __forceinline__ void slartg_f(float f, float g, float& c, float& s, float& r) {
#if NEW_SLARTG
  if (g == 0.0f) { c = 1.0f; s = 0.0f; r = f; }
  else if (f == 0.0f) { c = 0.0f; s = copysignf(1.0f, g); r = fabsf(g); }
  else {
    float d = sqrtf(f*f + g*g);
    c = fabsf(f) / d;
    r = copysignf(d, f);
    s = g / r;
  }
#else
  if (g == 0.0f) { c = 1.0f; s = 0.0f; r = f; }
  else if (f == 0.0f) { c = 0.0f; s = 1.0f; r = g; }
  else {
    float d = sqrtf(f*f + g*g);
    c = f / d; s = g / d; r = d;
    if (fabsf(f) > fabsf(g) && c < 0.0f) { c = -c; s = -s; r = -r; }
  }
#endif
}

__device__ __forceinline__ void slas2_f(float f, float g, float h, float& ssmin, float& ssmax) {
  float fa = fabsf(f), ga = fabsf(g), ha = fabsf(h);
  float fhmn = fminf(fa, ha), fhmx = fmaxf(fa, ha);
  if (fhmn == 0.0f) {
    ssmin = 0.0f;
    if (fhmx == 0.0f) ssmax = ga;
    else {
      float mn = fminf(fhmx, ga), mx = fmaxf(fhmx, ga);
      float qq = mn / mx;
      ssmax = mx * sqrtf(1.0f + qq*qq);
    }
  } else {
    if (ga < fhmx) {
      float as_ = 1.0f + fhmn/fhmx;
      float at_ = (fhmx - fhmn)/fhmx;
      float au_ = ga/fhmx; au_ = au_*au_;
      float c = 2.0f/(sqrtf(as_*as_ + au_) + sqrtf(at_*at_ + au_));
      ssmin = fhmn*c;
      ssmax = fhmx/c;
    } else {
      float au_ = fhmx/ga;
      if (au_ == 0.0f) {
        ssmin = (fhmn*fhmx)/ga;
        ssmax = ga;
      } else {
        float as_ = 1.0f + fhmn/fhmx;
        float at_ = (fhmx - fhmn)/fhmx;
        float t1 = as_*au_, t2 = at_*au_;
        float c = 1.0f/(sqrtf(1.0f + t1*t1) + sqrtf(1.0f + t2*t2));
        ssmin = (fhmn*c)*au_;
        ssmin = ssmin + ssmin;
        ssmax = ga/(c + c);
      }
    }
  }
}

__device__ void slasv2_f(float f, float g, float h,
                         float& ssmin, float& ssmax,
                         float& snr, float& csr, float& snl, float& csl) {
  const float eps = 5.9604645e-08f;
  float ft = f, fa = fabsf(f), ht = h, ha = fabsf(h);
  int pmax = 1;
  bool swap_ = (ha > fa);
  if (swap_) {
    pmax = 3;
    float tq = ft; ft = ht; ht = tq;
    tq = fa; fa = ha; ha = tq;
  }
  float gt = g, ga = fabsf(g);
  float clt = 0.f, crt = 0.f, slt = 0.f, srt = 0.f;
  if (ga == 0.0f) {
    ssmin = ha; ssmax = fa;
    clt = 1.0f; crt = 1.0f; slt = 0.0f; srt = 0.0f;
  } else {
    bool gasmal = true;
    if (ga > fa) {
      pmax = 2;
      if ((fa/ga) < eps) {
        gasmal = false;
        ssmax = ga;
        ssmin = (ha > 1.0f) ? (fa/(ga/ha)) : ((fa/ga)*ha);
        clt = 1.0f; slt = ht/gt; srt = 1.0f; crt = ft/gt;
      }
    }
    if (gasmal) {
      float dd = fa - ha;
      float l = (dd == fa) ? 1.0f : (dd/fa);
      float mr = gt/ft;
      float t = 2.0f - l;
      float mm2 = mr*mr, tt = t*t;
      float s_ = sqrtf(tt + mm2);
      float r_ = (l == 0.0f) ? fabsf(mr) : sqrtf(l*l + mm2);
      float a_ = 0.5f*(s_ + r_);
      ssmin = ha/a_;
      ssmax = fa*a_;
      if (mm2 == 0.0f) {
        if (l == 0.0f) t = copysignf(2.0f, ft)*copysignf(1.0f, gt);
        else t = gt/copysignf(dd, ft) + mr/t;
      } else {
        t = (mr/(s_ + t) + mr/(r_ + l))*(1.0f + a_);
      }
      float l2 = sqrtf(t*t + 4.0f);
      crt = 2.0f/l2;
      srt = t/l2;
      clt = (crt + srt*mr)/a_;
      slt = (ht/ft)*srt/a_;
    }
  }
  if (swap_) { csl = srt; snl = crt; csr = slt; snr = clt; }
  else       { csl = clt; snl = slt; csr = crt; snr = srt; }
  float tsign = 0.f;
  if (pmax == 1) tsign = copysignf(1.0f, csr)*copysignf(1.0f, csl)*copysignf(1.0f, f);
  if (pmax == 2) tsign = copysignf(1.0f, snr)*copysignf(1.0f, csl)*copysignf(1.0f, g);
  if (pmax == 3) tsign = copysignf(1.0f, snr)*copysignf(1.0f, snl)*copysignf(1.0f, h);
  ssmax = copysignf(ssmax, tsign);
  ssmin = copysignf(ssmin, tsign*copysignf(1.0f, f)*copysignf(1.0f, h));
}

__device__ __forceinline__ void rot_rows3(float mt[3][3], int r1, int r2, float c, float s) {
#pragma unroll
  for (int k = 0; k < 3; ++k) {
    float x = mt[r1][k], y = mt[r2][k];
    mt[r1][k] = c*x + s*y;
    mt[r2][k] = c*y - s*x;
  }
}
__device__ __forceinline__ void rot_cols3(float mt[3][3], int c1_, int c2_, float c, float s) {
#pragma unroll
  for (int k = 0; k < 3; ++k) {
    float x = mt[k][c1_], y = mt[k][c2_];
    mt[k][c1_] = c*x + s*y;
    mt[k][c2_] = c*y - s*x;
  }
}

#define D_(i) d[(i)-1]
#define E_(i) e[(i)-1]

__device__ void sbdsqr3(float* d, float* e, float u[3][3], float vt[3][3]) {
  const float eps  = 5.9604645e-08f;
  const float unfl = 1.17549435e-38f;
  const float tol  = 10.0f*eps;

  float sminoa = fabsf(d[0]);
  if (sminoa != 0.0f) {
    float mu = sminoa;
    mu = fabsf(d[1])*(mu/(mu + fabsf(e[0])));
    sminoa = fminf(sminoa, mu);
    if (sminoa != 0.0f) {
      mu = fabsf(d[2])*(mu/(mu + fabsf(e[1])));
      sminoa = fminf(sminoa, mu);
    }
  }
  sminoa = sminoa / sqrtf(3.0f);
  float thresh = fmaxf(tol*sminoa, 54.0f*unfl);

  int m = 3, oldll = -1, oldm = -1, idir = 0;
  int guard = 0;
  while (m > 1 && ++guard < 200) {
    float smax = fabsf(D_(m));
    int ll = 1; bool split = false;
    for (int lll = 1; lll <= m-1; ++lll) {
      int l2 = m - lll;
      float abss = fabsf(D_(l2)), abse = fabsf(E_(l2));
      if (abse <= thresh) { ll = l2; split = true; break; }
      smax = fmaxf(smax, fmaxf(abss, abse));
    }
    if (split) {
      E_(ll) = 0.0f;
      if (ll == m-1) { m = m - 1; continue; }
      ll = ll + 1;
    } else ll = 1;

    if (ll == m-1) {
      float sigmn, sigmx, sinr, cosr, sinl, cosl;
      slasv2_f(D_(m-1), E_(m-1), D_(m), sigmn, sigmx, sinr, cosr, sinl, cosl);
      D_(m-1) = sigmx; D_(m) = sigmn; E_(m-1) = 0.0f;
      rot_rows3(vt, m-2, m-1, cosr, sinr);
      rot_cols3(u,  m-2, m-1, cosl, sinl);
      m -= 2; continue;
    }

    if (ll > oldm || m < oldll)
      idir = (fabsf(D_(ll)) >= fabsf(D_(m))) ? 1 : 2;

    float sminl = 0.0f;
    bool deflated = false;
    if (idir == 1) {
      if (fabsf(E_(m-1)) <= tol*fabsf(D_(m))) { E_(m-1) = 0.0f; continue; }
      float mu = fabsf(D_(ll)); sminl = mu;
      for (int lll = ll; lll <= m-1; ++lll) {
        if (fabsf(E_(lll)) <= tol*mu) { E_(lll) = 0.0f; deflated = true; break; }
        mu = fabsf(D_(lll+1))*(mu/(mu + fabsf(E_(lll))));
        sminl = fminf(sminl, mu);
      }
    } else {
      if (fabsf(E_(ll)) <= tol*fabsf(D_(ll))) { E_(ll) = 0.0f; continue; }
      float mu = fabsf(D_(m)); sminl = mu;
      for (int lll = m-1; lll >= ll; --lll) {
        if (fabsf(E_(lll)) <= tol*mu) { E_(lll) = 0.0f; deflated = true; break; }
        mu = fabsf(D_(lll))*(mu/(mu + fabsf(E_(lll))));
        sminl = fminf(sminl, mu);
      }
    }
    if (deflated) continue;
    oldll = ll; oldm = m;

    float shift = 0.0f, rdum;
    if (!(3.0f*tol*(sminl/smax) <= fmaxf(eps, 0.01f*tol))) {
      float sll;
      if (idir == 1) { sll = fabsf(D_(ll)); slas2_f(D_(m-1), E_(m-1), D_(m), shift, rdum); }
      else           { sll = fabsf(D_(m));  slas2_f(D_(ll), E_(ll), D_(ll+1), shift, rdum); }
      if (sll > 0.0f) { float qq = shift/sll; if (qq*qq < eps) shift = 0.0f; }
    }

    if (shift == 0.0f) {
      if (idir == 1) {
        float cs = 1.0f, oldcs = 1.0f, sn = 0.0f, oldsn = 0.0f, r;
        float c1[2], s1[2], c2[2], s2[2];
        int k = 0;
        for (int i = ll; i <= m-1; ++i, ++k) {
          float fin = D_(i)*cs;
          slartg_f(fin, E_(i), cs, sn, r);
          if (i > ll) E_(i-1) = oldsn*r;
          float f2 = oldcs*r, g2 = D_(i+1)*sn;
          slartg_f(f2, g2, oldcs, oldsn, D_(i));
          c1[k] = cs; s1[k] = sn; c2[k] = oldcs; s2[k] = oldsn;
        }
        float h = D_(m)*cs;
        D_(m) = h*oldcs;
        E_(m-1) = h*oldsn;
        k = 0;
        for (int i = ll; i <= m-1; ++i, ++k) rot_rows3(vt, i-1, i, c1[k], s1[k]);
        k = 0;
        for (int i = ll; i <= m-1; ++i, ++k) rot_cols3(u, i-1, i, c2[k], s2[k]);
        if (fabsf(E_(m-1)) <= thresh) E_(m-1) = 0.0f;
      } else {
        float cs = 1.0f, oldcs = 1.0f, sn = 0.0f, oldsn = 0.0f, r;
        float c1[2], s1[2], c2[2], s2[2];
        for (int i = m; i >= ll+1; --i) {
          float fin = D_(i)*cs;
          slartg_f(fin, E_(i-1), cs, sn, r);
          if (i < m) E_(i) = oldsn*r;
          float f2 = oldcs*r, g2 = D_(i-1)*sn;
          slartg_f(f2, g2, oldcs, oldsn, D_(i));
          int slot = i - ll;
          c1[slot-1] = cs; s1[slot-1] = -sn; c2[slot-1] = oldcs; s2[slot-1] = -oldsn;
        }
        float h = D_(ll)*cs;
        D_(ll) = h*oldcs;
        E_(ll) = h*oldsn;
        for (int j = m-ll; j >= 1; --j) rot_rows3(vt, ll+j-2, ll+j-1, c2[j-1], s2[j-1]);
        for (int j = m-ll; j >= 1; --j) rot_cols3(u,  ll+j-2, ll+j-1, c1[j-1], s1[j-1]);
        if (fabsf(E_(ll)) <= thresh) E_(ll) = 0.0f;
      }
    } else {
      if (idir == 1) {
        float f = (fabsf(D_(ll)) - shift)*(copysignf(1.0f, D_(ll)) + shift/D_(ll));
        float g = E_(ll);
        float cr, sr, cl, sl, r;
        float c1[2], s1[2], c2[2], s2[2];
        int k = 0;
        for (int i = ll; i <= m-1; ++i, ++k) {
          slartg_f(f, g, cr, sr, r);
          if (i > ll) E_(i-1) = r;
          f = cr*D_(i) + sr*E_(i);
          E_(i) = cr*E_(i) - sr*D_(i);
          g = sr*D_(i+1);
          D_(i+1) = cr*D_(i+1);
          slartg_f(f, g, cl, sl, r);
          D_(i) = r;
          f = cl*E_(i) + sl*D_(i+1);
          D_(i+1) = cl*D_(i+1) - sl*E_(i);
          if (i < m-1) { g = sl*E_(i+1); E_(i+1) = cl*E_(i+1); }
          c1[k] = cr; s1[k] = sr; c2[k] = cl; s2[k] = sl;
        }
        E_(m-1) = f;
        k = 0;
        for (int i = ll; i <= m-1; ++i, ++k) rot_rows3(vt, i-1, i, c1[k], s1[k]);
        k = 0;
        for (int i = ll; i <= m-1; ++i, ++k) rot_cols3(u, i-1, i, c2[k], s2[k]);
        if (fabsf(E_(m-1)) <= thresh) E_(m-1) = 0.0f;
      } else {
        float f = (fabsf(D_(m)) - shift)*(copysignf(1.0f, D_(m)) + shift/D_(m));
        float g = E_(m-1);
        float cr, sr, cl, sl, r;
        float c1[2], s1[2], c2[2], s2[2];
        for (int i = m; i >= ll+1; --i) {
          slartg_f(f, g, cr, sr, r);
          if (i < m) E_(i) = r;
          f = cr*D_(i) + sr*E_(i-1);
          E_(i-1) = cr*E_(i-1) - sr*D_(i);
          g = sr*D_(i-1);
          D_(i-1) = cr*D_(i-1);
          slartg_f(f, g, cl, sl, r);
          D_(i) = r;
          f = cl*E_(i-1) + sl*D_(i-1);
          D_(i-1) = cl*D_(i-1) - sl*E_(i-1);
          if (i > ll+1) { g = sl*E_(i-2); E_(i-2) = cl*E_(i-2); }
          int slot = i - ll;
          c1[slot-1] = cr; s1[slot-1] = -sr; c2[slot-1] = cl; s2[slot-1] = -sl;
        }
        E_(ll) = f;
        if (fabsf(E_(ll)) <= thresh) E_(ll) = 0.0f;
        for (int j = m-ll; j >= 1; --j) rot_rows3(vt, ll+j-2, ll+j-1, c2[j-1], s2[j-1]);
        for (int j = m-ll; j >= 1; --j) rot_cols3(u,  ll+j-2, ll+j-1, c1[j-1], s1[j-1]);
      }
    }
  }

  for (int i = 1; i <= 3; ++i) {
    if (D_(i) < 0.0f) {
      D_(i) = -D_(i);
#pragma unroll
      for (int k = 0; k < 3; ++k) vt[i-1][k] = -vt[i-1][k];
    }
  }
  for (int i = 1; i <= 2; ++i) {
    int isub = 1; float smn = D_(1);
    for (int j = 2; j <= 4-i; ++j) {
      if (D_(j) <= smn) { isub = j; smn = D_(j); }
    }
    if (isub != 4-i) {
      D_(isub) = D_(4-i); D_(4-i) = smn;
#pragma unroll
      for (int k = 0; k < 3; ++k) { float tq = vt[isub-1][k]; vt[isub-1][k] = vt[4-i-1][k]; vt[4-i-1][k] = tq; }
#pragma unroll
      for (int k = 0; k < 3; ++k) { float tq = u[k][isub-1]; u[k][isub-1] = u[k][4-i-1]; u[k][4-i-1] = tq; }
    }
  }
}

__device__ void svd3_gesdd(const float Ain[3][3], float u[3][3], float vt[3][3]) {
  float a[3][3];
#pragma unroll
  for (int i = 0; i < 3; ++i)
#pragma unroll
    for (int j = 0; j < 3; ++j) a[i][j] = Ain[i][j];

  float d[3], e[2];
  float tq0 = 0.f, tq1 = 0.f, tp0 = 0.f;
  float v0a = 0.f, v0b = 0.f, v1a = 0.f, p0a = 0.f;

  {
    float alpha = a[0][0];
    float xn = sqrtf(a[1][0]*a[1][0] + a[2][0]*a[2][0]);
    if (xn == 0.0f) { tq0 = 0.0f; d[0] = alpha; }
    else {
      float beta = -copysignf(sqrtf(alpha*alpha + xn*xn), alpha);
      tq0 = (beta - alpha)/beta;
      float sc = 1.0f/(alpha - beta);
      v0a = a[1][0]*sc; v0b = a[2][0]*sc;
      d[0] = beta;
    }
#pragma unroll
    for (int j = 1; j < 3; ++j) {
      float w = (a[0][j] + v0a*a[1][j] + v0b*a[2][j])*tq0;
      a[0][j] -= w; a[1][j] -= w*v0a; a[2][j] -= w*v0b;
    }
  }
  {
    float alpha = a[0][1];
    float xn = fabsf(a[0][2]);
    if (xn == 0.0f) { tp0 = 0.0f; e[0] = alpha; }
    else {
      float beta = -copysignf(sqrtf(alpha*alpha + xn*xn), alpha);
      tp0 = (beta - alpha)/beta;
      p0a = a[0][2]/(alpha - beta);
      e[0] = beta;
    }
#pragma unroll
    for (int i = 1; i < 3; ++i) {
      float w = (a[i][1] + p0a*a[i][2])*tp0;
      a[i][1] -= w; a[i][2] -= w*p0a;
    }
  }
  {
    float alpha = a[1][1];
    float xn = fabsf(a[2][1]);
    if (xn == 0.0f) { tq1 = 0.0f; d[1] = alpha; }
    else {
      float beta = -copysignf(sqrtf(alpha*alpha + xn*xn), alpha);
      tq1 = (beta - alpha)/beta;
      v1a = a[2][1]/(alpha - beta);
      d[1] = beta;
    }
    float w = (a[1][2] + v1a*a[2][2])*tq1;
    a[1][2] -= w; a[2][2] -= w*v1a;
  }
  e[1] = a[1][2];
  d[2] = a[2][2];

  float ub[3][3] = {{1,0,0},{0,1,0},{0,0,1}};
  float vb[3][3] = {{1,0,0},{0,1,0},{0,0,1}};
  sbdsqr3(d, e, ub, vb);

#pragma unroll
  for (int j = 0; j < 3; ++j) {
    float w = (ub[1][j] + v1a*ub[2][j])*tq1;
    ub[1][j] -= w; ub[2][j] -= w*v1a;
  }
#pragma unroll
  for (int j = 0; j < 3; ++j) {
    float w = (ub[0][j] + v0a*ub[1][j] + v0b*ub[2][j])*tq0;
    ub[0][j] -= w; ub[1][j] -= w*v0a; ub[2][j] -= w*v0b;
  }
#pragma unroll
  for (int i = 0; i < 3; ++i) {
    float w = (vb[i][1] + p0a*vb[i][2])*tp0;
    vb[i][1] -= w; vb[i][2] -= w*p0a;
  }
#pragma unroll
  for (int i = 0; i < 3; ++i)
#pragma unroll
    for (int j = 0; j < 3; ++j) { u[i][j] = ub[i][j]; vt[i][j] = vb[i][j]; }
}

// =============================================================================
// bf16 helpers (RNE, manual — avoids type plumbing)
// =============================================================================
__device__ __forceinline__ unsigned short f2bf(float x) {
  unsigned int u = __float_as_uint(x);
  unsigned int r = (u + 0x7FFFu + ((u >> 16) & 1u)) >> 16;
  return (unsigned short)r;
}
__device__ __forceinline__ float bf2f(unsigned short h) {
  return __uint_as_float(((unsigned int)h) << 16);
}

// =============================================================================
// Kernel 0: pack Q (x0.25, split hi/lo) and K (split hi/lo) into MFMA-operand
// rows of 64 bf16 (128 B):  Qrow = [qh | qh | ql | 0],  Krow = [kh | kl | kh | 0]
// so that  A1=[kh|kl] x B1=[qh|qh]  +  A2=[kh|0] x B2=[ql|0]
//        = kh*qh + kl*qh + kh*ql  ~=  q*k  (residual ql*kl ~ 2^-16 rel).
// grid 128 x 256 threads: one thread per (b, n).
// =============================================================================
__global__ __launch_bounds__(256)
void pack_kernel(const float* __restrict__ srcE, const float* __restrict__ tgtE,
                 unsigned short* __restrict__ Qp, unsigned short* __restrict__ Kp) {
  const int g = blockIdx.x*256 + threadIdx.x;   // 32768 = 16*2048
  const int b = g >> 11, n = g & 2047;
  const float* qs = srcE + (size_t)b*16*2048 + n;
  const float* ks = tgtE + (size_t)b*16*2048 + n;

  unsigned short qrow[64], krow[64];
#pragma unroll
  for (int dd = 0; dd < 16; ++dd) {
    float q = qs[dd*2048] * 0.25f;           // fold 1/sqrt(d_k)=1/4 into Q
    unsigned short qh = f2bf(q);
    unsigned short ql = f2bf(q - bf2f(qh));
    qrow[dd] = qh; qrow[16+dd] = qh; qrow[32+dd] = ql; qrow[48+dd] = 0;

    float k = ks[dd*2048];
    unsigned short kh = f2bf(k);
    unsigned short kl = f2bf(k - bf2f(kh));
    krow[dd] = kh; krow[16+dd] = kl; krow[32+dd] = kh; krow[48+dd] = 0;
  }
  uint4* qdst = (uint4*)(Qp + (size_t)g*64);
  uint4* kdst = (uint4*)(Kp + (size_t)g*64);
#pragma unroll
  for (int i = 0; i < 8; ++i) { qdst[i] = ((uint4*)qrow)[i]; kdst[i] = ((uint4*)krow)[i]; }
}

// =============================================================================
// Kernel 1: MFMA flash attention + per-(b,ntile) partial stats.
// grid = 256 blocks: bid = nt*16 + b  (keeps one batch's K-stream on one XCD).
// block = 512 threads (8 waves). Wave w owns 2 m-tiles per 256-m chunk and
// loops over all 8 n-tiles; Q-frags held in registers; A-frags from LDS
// (144 B row stride => BW-bound b128 reads); P stays f32 (exp + PV in VALU).
// =============================================================================
__global__ __launch_bounds__(512)
void corr_kernel(const unsigned short* __restrict__ Qp, const unsigned short* __restrict__ Kp,
                 const float* __restrict__ src, const float* __restrict__ tgt,
                 float* __restrict__ ws) {
  const int bid = blockIdx.x;
  const int b   = bid & 15;          // b = bid%16 -> bid%8 fixed per batch pair
  const int nt  = bid >> 4;
  const int tid = threadIdx.x;
  const int w   = tid >> 6;
  const int L   = tid & 63;
  const int lg  = L >> 4;            // lane group 0..3
  const int ll  = L & 15;            // lane low 0..15

  __shared__ __align__(16) char  Alds[256*144];       // 36.9 KB staged K rows
  __shared__ __align__(16) float Vlds[256][4];        // 4 KB
  __shared__ __align__(16) float partial[8][128][4];  // 16 KB
  __shared__ float red[8][16];

  const unsigned short* Qb = Qp + (size_t)b*2048*64;
  const unsigned short* Kb = Kp + (size_t)b*2048*64;

  // ---- Q-fragments for this block's 8 n-tiles (held in registers) ----
  bf16x8 bq1[8], bq2[8];
#pragma unroll
  for (int t2 = 0; t2 < 8; ++t2) {
    const unsigned short* qr = Qb + (size_t)(nt*128 + t2*16 + ll)*64;
    bq1[t2] = *(const bf16x8*)(qr + lg*8);        // k in [0,32):  [qh|qh]
    bq2[t2] = *(const bf16x8*)(qr + 32 + lg*8);   // k in [32,64): [ql|0]
  }

  f32x4 acc[8];
#pragma unroll
  for (int t2 = 0; t2 < 8; ++t2) acc[t2] = (f32x4){0.f, 0.f, 0.f, 0.f};

  for (int chunk = 0; chunk < 8; ++chunk) {
    __syncthreads();
    // ---- stage 256 K rows (32 KB) + 256 V rows ----
    {
      const char* ksrc = (const char*)(Kb + (size_t)chunk*256*64);
#pragma unroll
      for (int i = 0; i < 4; ++i) {
        int f = (tid + i*512)*16;                   // flat byte in 32 KB chunk
        int row = f >> 7, col = f & 127;
        *(uint4*)(Alds + row*144 + col) = *(const uint4*)(ksrc + f);
      }
      if (tid < 256) {
        int m = chunk*256 + tid;
        const float* vp = tgt + (size_t)b*3*2048 + m;
        float4 vv = make_float4(vp[0], vp[2048], vp[4096], 0.f);
        *(float4*)&Vlds[tid][0] = vv;
      }
    }
    __syncthreads();

#pragma unroll
    for (int mt = 0; mt < 2; ++mt) {
      const int rowb = (w*2 + mt)*16;               // m-tile base row in chunk
      const char* arow = Alds + (size_t)(rowb + ll)*144;
      bf16x8 a1 = *(const bf16x8*)(arow + lg*16);        // [kh|kl]
      bf16x8 a2 = *(const bf16x8*)(arow + 64 + lg*16);   // [kh|0]
      float4 v0 = *(const float4*)&Vlds[rowb + lg*4 + 0][0];
      float4 v1 = *(const float4*)&Vlds[rowb + lg*4 + 1][0];
      float4 v2 = *(const float4*)&Vlds[rowb + lg*4 + 2][0];
      float4 v3 = *(const float4*)&Vlds[rowb + lg*4 + 3][0];
#pragma unroll
      for (int t2 = 0; t2 < 8; ++t2) {
        f32x4 c = (f32x4){0.f, 0.f, 0.f, 0.f};
        c = __builtin_amdgcn_mfma_f32_16x16x32_bf16(a1, bq1[t2], c, 0, 0, 0);
        c = __builtin_amdgcn_mfma_f32_16x16x32_bf16(a2, bq2[t2], c, 0, 0, 0);
        // C/D: col n = ll, row m = rowb + lg*4 + r  (r = reg idx)
        float e0 = __expf(c.x), e1 = __expf(c.y), e2 = __expf(c.z), e3 = __expf(c.w);
        acc[t2].x += (e0 + e1) + (e2 + e3);
        acc[t2].y += e0*v0.x + e1*v1.x + e2*v2.x + e3*v3.x;
        acc[t2].z += e0*v0.y + e1*v1.y + e2*v2.y + e3*v3.y;
        acc[t2].w += e0*v0.z + e1*v1.z + e2*v2.z + e3*v3.z;
      }
    }
  }

  // ---- reduce across the 4 lane-groups (rows of C live on lg) ----
#pragma unroll
  for (int t2 = 0; t2 < 8; ++t2) {
    float x = acc[t2].x, y = acc[t2].y, z = acc[t2].z, ww = acc[t2].w;
    x += __shfl_xor(x, 16); x += __shfl_xor(x, 32);
    y += __shfl_xor(y, 16); y += __shfl_xor(y, 32);
    z += __shfl_xor(z, 16); z += __shfl_xor(z, 32);
    ww += __shfl_xor(ww, 16); ww += __shfl_xor(ww, 32);
    acc[t2] = (f32x4){x, y, z, ww};
  }
  __syncthreads();
  if (lg == 0) {
#pragma unroll
    for (int t2 = 0; t2 < 8; ++t2)
      *(float4*)&partial[w][t2*16 + ll][0] =
          make_float4(acc[t2].x, acc[t2].y, acc[t2].z, acc[t2].w);
  }
  __syncthreads();

  // ---- per-n finish + 15-value block reduction ----
  float vals[15];
#pragma unroll
  for (int k = 0; k < 15; ++k) vals[k] = 0.f;
  if (tid < 128) {
    float4 s4 = make_float4(0.f, 0.f, 0.f, 0.f);
#pragma unroll
    for (int w2 = 0; w2 < 8; ++w2) {
      float4 p = *(const float4*)&partial[w2][tid][0];
      s4.x += p.x; s4.y += p.y; s4.z += p.z; s4.w += p.w;
    }
    float inv = 1.0f / s4.x;
    float c0 = s4.y*inv, c1 = s4.z*inv, c2 = s4.w*inv;
    int n = nt*128 + tid;
    const float* sp = src + (size_t)b*3*2048;
    float s0v = sp[n], s1v = sp[2048+n], s2v = sp[4096+n];
    vals[0]=c0; vals[1]=c1; vals[2]=c2; vals[3]=s0v; vals[4]=s1v; vals[5]=s2v;
    vals[6]=s0v*c0; vals[7]=s0v*c1; vals[8]=s0v*c2;
    vals[9]=s1v*c0; vals[10]=s1v*c1; vals[11]=s1v*c2;
    vals[12]=s2v*c0; vals[13]=s2v*c1; vals[14]=s2v*c2;
  }
#pragma unroll
  for (int k = 0; k < 15; ++k) {
    float v = vals[k];
    v += __shfl_xor(v, 1);  v += __shfl_xor(v, 2);  v += __shfl_xor(v, 4);
    v += __shfl_xor(v, 8);  v += __shfl_xor(v, 16); v += __shfl_xor(v, 32);
    vals[k] = v;
  }
  if (L == 0) {
#pragma unroll
    for (int k = 0; k < 15; ++k) red[w][k] = vals[k];
  }
  __syncthreads();
  if (tid < 15) {
    float t = 0.0f;
#pragma unroll
    for (int w2 = 0; w2 < 8; ++w2) t += red[w2][tid];
    ws[bid*16 + tid] = t;
  }
}

// =============================================================================
// Kernel 2: per-batch final reduction + SVD.  One block per batch (16 blocks),
// lane 0 runs the LAPACK-faithful SVD; no cross-batch divergence serialization.
// =============================================================================
__global__ void finalize_kernel(const float* __restrict__ ws, float* __restrict__ out) {
  const int b = blockIdx.x;
  const int t = threadIdx.x;

  float a = 0.0f;
  if (t < 15) {
#pragma unroll
    for (int ntile = 0; ntile < 16; ++ntile)
      a += ws[(ntile*16 + b)*16 + t];
  }
  float acc[15];
#pragma unroll
  for (int k = 0; k < 15; ++k) acc[k] = __shfl(a, k);

  if (t == 0) {
    const float invN = 1.0f/2048.0f;
    float Sc[3] = {acc[0], acc[1], acc[2]};
    float Ss[3] = {acc[3], acc[4], acc[5]};
    float cm[3] = {Sc[0]*invN, Sc[1]*invN, Sc[2]*invN};
    float sm[3] = {Ss[0]*invN, Ss[1]*invN, Ss[2]*invN};

    float A[3][3];
#pragma unroll
    for (int i = 0; i < 3; ++i)
#pragma unroll
      for (int j = 0; j < 3; ++j)
        A[i][j] = acc[6 + i*3 + j] - Ss[i]*cm[j];

    float u[3][3], vt[3][3];
    svd3_gesdd(A, u, vt);

    float R[3][3];
#pragma unroll
    for (int i = 0; i < 3; ++i)
#pragma unroll
      for (int k = 0; k < 3; ++k)
        R[i][k] = vt[i][0]*u[k][0] + vt[i][1]*u[k][1] + vt[i][2]*u[k][2];

    float det = R[0][0]*(R[1][1]*R[2][2] - R[1][2]*R[2][1])
              - R[0][1]*(R[1][0]*R[2][2] - R[1][2]*R[2][0])
              + R[0][2]*(R[1][0]*R[2][1] - R[1][1]*R[2][0]);

    if (det < 0.0f) {
#pragma unroll
      for (int i = 0; i < 3; ++i)
#pragma unroll
        for (int k = 0; k < 3; ++k)
          R[i][k] -= 2.0f*vt[i][2]*u[k][2];
    }

    float tv[3];
#pragma unroll
    for (int i = 0; i < 3; ++i)
      tv[i] = -(R[i][0]*sm[0] + R[i][1]*sm[1] + R[i][2]*sm[2]) + cm[i];

#pragma unroll
    for (int i = 0; i < 3; ++i)
#pragma unroll
      for (int j = 0; j < 3; ++j)
        out[b*9 + i*3 + j] = R[i][j];
#pragma unroll
    for (int i = 0; i < 3; ++i)
      out[144 + b*3 + i] = tv[i];
  }
}

extern "C" void kernel_launch(void* const* d_in, const int* in_sizes, int n_in,
                              void* d_out, int out_size, void* d_ws, size_t ws_size,
                              hipStream_t stream) {
  const float* srcE = (const float*)d_in[0];
  const float* tgtE = (const float*)d_in[1];
  const float* src  = (const float*)d_in[2];
  const float* tgt  = (const float*)d_in[3];
  float* out = (float*)d_out;

  // ws layout: [0,16KB) corr partials; then Qpack (4 MB); then Kpack (4 MB).
  float* part = (float*)d_ws;
  unsigned short* Qp = (unsigned short*)((char*)d_ws + 16384);
  unsigned short* Kp = (unsigned short*)((char*)d_ws + 16384 + (size_t)16*2048*64*2);

  hipLaunchKernelGGL(pack_kernel, dim3(128), dim3(256), 0, stream, srcE, tgtE, Qp, Kp);
  hipLaunchKernelGGL(corr_kernel, dim3(256), dim3(512), 0, stream, Qp, Kp, src, tgt, part);
  hipLaunchKernelGGL(finalize_kernel, dim3(16), dim3(64), 0, stream, part, out);
}

// Round 3
// 57.902 us; speedup vs baseline: 1.7337x; 1.0847x over previous
//
#include <hip/hip_runtime.h>
#include <math.h>

// LAPACK >= 3.10 slartg convention (c >= 0). Flip to 0 to emulate <= 3.9.
#define NEW_SLARTG 1

typedef __attribute__((ext_vector_type(8))) short bf16x8;
typedef __attribute__((ext_vector_type(4))) float f32x4;

// =============================================================================
// LAPACK sgesdd emulation for 3x3 (f32), faithful sign conventions. (UNCHANGED)
// =============================================================================

__device__ __forceinline__ void slartg_f(float f, float g, float& c, float& s, float& r) {
#if NEW_SLARTG
  if (g == 0.0f) { c = 1.0f; s = 0.0f; r = f; }
  else if (f == 0.0f) { c = 0.0f; s = copysignf(1.0f, g); r = fabsf(g); }
  else {
    float d = sqrtf(f*f + g*g);
    c = fabsf(f) / d;
    r = copysignf(d, f);
    s = g / r;
  }
#else
  if (g == 0.0f) { c = 1.0f; s = 0.0f; r = f; }
  else if (f == 0.0f) { c = 0.0f; s = 1.0f; r = g; }
  else {
    float d = sqrtf(f*f + g*g);
    c = f / d; s = g / d; r = d;
    if (fabsf(f) > fabsf(g) && c < 0.0f) { c = -c; s = -s; r = -r; }
  }
#endif
}

__device__ __forceinline__ void slas2_f(float f, float g, float h, float& ssmin, float& ssmax) {
  float fa = fabsf(f), ga = fabsf(g), ha = fabsf(h);
  float fhmn = fminf(fa, ha), fhmx = fmaxf(fa, ha);
  if (fhmn == 0.0f) {
    ssmin = 0.0f;
    if (fhmx == 0.0f) ssmax = ga;
    else {
      float mn = fminf(fhmx, ga), mx = fmaxf(fhmx, ga);
      float qq = mn / mx;
      ssmax = mx * sqrtf(1.0f + qq*qq);
    }
  } else {
    if (ga < fhmx) {
      float as_ = 1.0f + fhmn/fhmx;
      float at_ = (fhmx - fhmn)/fhmx;
      float au_ = ga/fhmx; au_ = au_*au_;
      float c = 2.0f/(sqrtf(as_*as_ + au_) + sqrtf(at_*at_ + au_));
      ssmin = fhmn*c;
      ssmax = fhmx/c;
    } else {
      float au_ = fhmx/ga;
      if (au_ == 0.0f) {
        ssmin = (fhmn*fhmx)/ga;
        ssmax = ga;
      } else {
        float as_ = 1.0f + fhmn/fhmx;
        float at_ = (fhmx - fhmn)/fhmx;
        float t1 = as_*au_, t2 = at_*au_;
        float c = 1.0f/(sqrtf(1.0f + t1*t1) + sqrtf(1.0f + t2*t2));
        ssmin = (fhmn*c)*au_;
        ssmin = ssmin + ssmin;
        ssmax = ga/(c + c);
      }
    }
  }
}

__device__ void slasv2_f(float f, float g, float h,
                         float& ssmin, float& ssmax,
                         float& snr, float& csr, float& snl, float& csl) {
  const float eps = 5.9604645e-08f;
  float ft = f, fa = fabsf(f), ht = h, ha = fabsf(h);
  int pmax = 1;
  bool swap_ = (ha > fa);
  if (swap_) {
    pmax = 3;
    float tq = ft; ft = ht; ht = tq;
    tq = fa; fa = ha; ha = tq;
  }
  float gt = g, ga = fabsf(g);
  float clt = 0.f, crt = 0.f, slt = 0.f, srt = 0.f;
  if (ga == 0.0f) {
    ssmin = ha; ssmax = fa;
    clt = 1.0f; crt = 1.0f; slt = 0.0f; srt = 0.0f;
  } else {
    bool gasmal = true;
    if (ga > fa) {
      pmax = 2;
      if ((fa/ga) < eps) {
        gasmal = false;
        ssmax = ga;
        ssmin = (ha > 1.0f) ? (fa/(ga/ha)) : ((fa/ga)*ha);
        clt = 1.0f; slt = ht/gt; srt = 1.0f; crt = ft/gt;
      }
    }
    if (gasmal) {
      float dd = fa - ha;
      float l = (dd == fa) ? 1.0f : (dd/fa);
      float mr = gt/ft;
      float t = 2.0f - l;
      float mm2 = mr*mr, tt = t*t;
      float s_ = sqrtf(tt + mm2);
      float r_ = (l == 0.0f) ? fabsf(mr) : sqrtf(l*l + mm2);
      float a_ = 0.5f*(s_ + r_);
      ssmin = ha/a_;
      ssmax = fa*a_;
      if (mm2 == 0.0f) {
        if (l == 0.0f) t = copysignf(2.0f, ft)*copysignf(1.0f, gt);
        else t = gt/copysignf(dd, ft) + mr/t;
      } else {
        t = (mr/(s_ + t) + mr/(r_ + l))*(1.0f + a_);
      }
      float l2 = sqrtf(t*t + 4.0f);
      crt = 2.0f/l2;
      srt = t/l2;
      clt = (crt + srt*mr)/a_;
      slt = (ht/ft)*srt/a_;
    }
  }
  if (swap_) { csl = srt; snl = crt; csr = slt; snr = clt; }
  else       { csl = clt; snl = slt; csr = crt; snr = srt; }
  float tsign = 0.f;
  if (pmax == 1) tsign = copysignf(1.0f, csr)*copysignf(1.0f, csl)*copysignf(1.0f, f);
  if (pmax == 2) tsign = copysignf(1.0f, snr)*copysignf(1.0f, csl)*copysignf(1.0f, g);
  if (pmax == 3) tsign = copysignf(1.0f, snr)*copysignf(1.0f, snl)*copysignf(1.0f, h);
  ssmax = copysignf(ssmax, tsign);
  ssmin = copysignf(ssmin, tsign*copysignf(1.0f, f)*copysignf(1.0f, h));
}

__device__ __forceinline__ void rot_rows3(float mt[3][3], int r1, int r2, float c, float s) {
#pragma unroll
  for (int k = 0; k < 3; ++k) {
    float x = mt[r1][k], y = mt[r2][k];
    mt[r1][k] = c*x + s*y;
    mt[r2][k] = c*y - s*x;
  }
}
__device__ __forceinline__ void rot_cols3(float mt[3][3], int c1_, int c2_, float c, float s) {
#pragma unroll
  for (int k = 0; k < 3; ++k) {
    float x = mt[k][c1_], y = mt[k][c2_];
    mt[k][c1_] = c*x + s*y;
    mt[k][c2_] = c*y - s*x;
  }
}

#define D_(i) d[(i)-1]
#define E_(i) e[(i)-1]

__device__ void sbdsqr3(float* d, float* e, float u[3][3], float vt[3][3]) {
  const float eps  = 5.9604645e-08f;
  const float unfl = 1.17549435e-38f;
  const float tol  = 10.0f*eps;

  float sminoa = fabsf(d[0]);
  if (sminoa != 0.0f) {
    float mu = sminoa;
    mu = fabsf(d[1])*(mu/(mu + fabsf(e[0])));
    sminoa = fminf(sminoa, mu);
    if (sminoa != 0.0f) {
      mu = fabsf(d[2])*(mu/(mu + fabsf(e[1])));
      sminoa = fminf(sminoa, mu);
    }
  }
  sminoa = sminoa / sqrtf(3.0f);
  float thresh = fmaxf(tol*sminoa, 54.0f*unfl);

  int m = 3, oldll = -1, oldm = -1, idir = 0;
  int guard = 0;
  while (m > 1 && ++guard < 200) {
    float smax = fabsf(D_(m));
    int ll = 1; bool split = false;
    for (int lll = 1; lll <= m-1; ++lll) {
      int l2 = m - lll;
      float abss = fabsf(D_(l2)), abse = fabsf(E_(l2));
      if (abse <= thresh) { ll = l2; split = true; break; }
      smax = fmaxf(smax, fmaxf(abss, abse));
    }
    if (split) {
      E_(ll) = 0.0f;
      if (ll == m-1) { m = m - 1; continue; }
      ll = ll + 1;
    } else ll = 1;

    if (ll == m-1) {
      float sigmn, sigmx, sinr, cosr, sinl, cosl;
      slasv2_f(D_(m-1), E_(m-1), D_(m), sigmn, sigmx, sinr, cosr, sinl, cosl);
      D_(m-1) = sigmx; D_(m) = sigmn; E_(m-1) = 0.0f;
      rot_rows3(vt, m-2, m-1, cosr, sinr);
      rot_cols3(u,  m-2, m-1, cosl, sinl);
      m -= 2; continue;
    }

    if (ll > oldm || m < oldll)
      idir = (fabsf(D_(ll)) >= fabsf(D_(m))) ? 1 : 2;

    float sminl = 0.0f;
    bool deflated = false;
    if (idir == 1) {
      if (fabsf(E_(m-1)) <= tol*fabsf(D_(m))) { E_(m-1) = 0.0f; continue; }
      float mu = fabsf(D_(ll)); sminl = mu;
      for (int lll = ll; lll <= m-1; ++lll) {
        if (fabsf(E_(lll)) <= tol*mu) { E_(lll) = 0.0f; deflated = true; break; }
        mu = fabsf(D_(lll+1))*(mu/(mu + fabsf(E_(lll))));
        sminl = fminf(sminl, mu);
      }
    } else {
      if (fabsf(E_(ll)) <= tol*fabsf(D_(ll))) { E_(ll) = 0.0f; continue; }
      float mu = fabsf(D_(m)); sminl = mu;
      for (int lll = m-1; lll >= ll; --lll) {
        if (fabsf(E_(lll)) <= tol*mu) { E_(lll) = 0.0f; deflated = true; break; }
        mu = fabsf(D_(lll))*(mu/(mu + fabsf(E_(lll))));
        sminl = fminf(sminl, mu);
      }
    }
    if (deflated) continue;
    oldll = ll; oldm = m;

    float shift = 0.0f, rdum;
    if (!(3.0f*tol*(sminl/smax) <= fmaxf(eps, 0.01f*tol))) {
      float sll;
      if (idir == 1) { sll = fabsf(D_(ll)); slas2_f(D_(m-1), E_(m-1), D_(m), shift, rdum); }
      else           { sll = fabsf(D_(m));  slas2_f(D_(ll), E_(ll), D_(ll+1), shift, rdum); }
      if (sll > 0.0f) { float qq = shift/sll; if (qq*qq < eps) shift = 0.0f; }
    }

    if (shift == 0.0f) {
      if (idir == 1) {
        float cs = 1.0f, oldcs = 1.0f, sn = 0.0f, oldsn = 0.0f, r;
        float c1[2], s1[2], c2[2], s2[2];
        int k = 0;
        for (int i = ll; i <= m-1; ++i, ++k) {
          float fin = D_(i)*cs;
          slartg_f(fin, E_(i), cs, sn, r);
          if (i > ll) E_(i-1) = oldsn*r;
          float f2 = oldcs*r, g2 = D_(i+1)*sn;
          slartg_f(f2, g2, oldcs, oldsn, D_(i));
          c1[k] = cs; s1[k] = sn; c2[k] = oldcs; s2[k] = oldsn;
        }
        float h = D_(m)*cs;
        D_(m) = h*oldcs;
        E_(m-1) = h*oldsn;
        k = 0;
        for (int i = ll; i <= m-1; ++i, ++k) rot_rows3(vt, i-1, i, c1[k], s1[k]);
        k = 0;
        for (int i = ll; i <= m-1; ++i, ++k) rot_cols3(u, i-1, i, c2[k], s2[k]);
        if (fabsf(E_(m-1)) <= thresh) E_(m-1) = 0.0f;
      } else {
        float cs = 1.0f, oldcs = 1.0f, sn = 0.0f, oldsn = 0.0f, r;
        float c1[2], s1[2], c2[2], s2[2];
        for (int i = m; i >= ll+1; --i) {
          float fin = D_(i)*cs;
          slartg_f(fin, E_(i-1), cs, sn, r);
          if (i < m) E_(i) = oldsn*r;
          float f2 = oldcs*r, g2 = D_(i-1)*sn;
          slartg_f(f2, g2, oldcs, oldsn, D_(i));
          int slot = i - ll;
          c1[slot-1] = cs; s1[slot-1] = -sn; c2[slot-1] = oldcs; s2[slot-1] = -oldsn;
        }
        float h = D_(ll)*cs;
        D_(ll) = h*oldcs;
        E_(ll) = h*oldsn;
        for (int j = m-ll; j >= 1; --j) rot_rows3(vt, ll+j-2, ll+j-1, c2[j-1], s2[j-1]);
        for (int j = m-ll; j >= 1; --j) rot_cols3(u,  ll+j-2, ll+j-1, c1[j-1], s1[j-1]);
        if (fabsf(E_(ll)) <= thresh) E_(ll) = 0.0f;
      }
    } else {
      if (idir == 1) {
        float f = (fabsf(D_(ll)) - shift)*(copysignf(1.0f, D_(ll)) + shift/D_(ll));
        float g = E_(ll);
        float cr, sr, cl, sl, r;
        float c1[2], s1[2], c2[2], s2[2];
        int k = 0;
        for (int i = ll; i <= m-1; ++i, ++k) {
          slartg_f(f, g, cr, sr, r);
          if (i > ll) E_(i-1) = r;
          f = cr*D_(i) + sr*E_(i);
          E_(i) = cr*E_(i) - sr*D_(i);
          g = sr*D_(i+1);
          D_(i+1) = cr*D_(i+1);
          slartg_f(f, g, cl, sl, r);
          D_(i) = r;
          f = cl*E_(i) + sl*D_(i+1);
          D_(i+1) = cl*D_(i+1) - sl*E_(i);
          if (i < m-1) { g = sl*E_(i+1); E_(i+1) = cl*E_(i+1); }
          c1[k] = cr; s1[k] = sr; c2[k] = cl; s2[k] = sl;
        }
        E_(m-1) = f;
        k = 0;
        for (int i = ll; i <= m-1; ++i, ++k) rot_rows3(vt, i-1, i, c1[k], s1[k]);
        k = 0;
        for (int i = ll; i <= m-1; ++i, ++k) rot_cols3(u, i-1, i, c2[k], s2[k]);
        if (fabsf(E_(m-1)) <= thresh) E_(m-1) = 0.0f;
      } else {
        float f = (fabsf(D_(m)) - shift)*(copysignf(1.0f, D_(m)) + shift/D_(m));
        float g = E_(m-1);
        float cr, sr, cl, sl, r;
        float c1[2], s1[2], c2[2], s2[2];
        for (int i = m; i >= ll+1; --i) {
          slartg_f(f, g, cr, sr, r);
          if (i < m) E_(i) = r;
          f = cr*D_(i) + sr*E_(i-1);
          E_(i-1) = cr*E_(i-1) - sr*D_(i);
          g = sr*D_(i-1);
          D_(i-1) = cr*D_(i-1);
          slartg_f(f, g, cl, sl, r);
          D_(i) = r;
          f = cl*E_(i-1) + sl*D_(i-1);
          D_(i-1) = cl*D_(i-1) - sl*E_(i-1);
          if (i > ll+1) { g = sl*E_(i-2); E_(i-2) = cl*E_(i-2); }
          int slot = i - ll;
          c1[slot-1] = cr; s1[slot-1] = -sr; c2[slot-1] = cl; s2[slot-1] = -sl;
        }
        E_(ll) = f;
        if (fabsf(E_(ll)) <= thresh) E_(ll) = 0.0f;
        for (int j = m-ll; j >= 1; --j) rot_rows3(vt, ll+j-2, ll+j-1, c2[j-1], s2[j-1]);
        for (int j = m-ll; j >= 1; --j) rot_cols3(u,  ll+j-2, ll+j-1, c1[j-1], s1[j-1]);
      }
    }
  }

  for (int i = 1; i <= 3; ++i) {
    if (D_(i) < 0.0f) {
      D_(i) = -D_(i);
#pragma unroll
      for (int k = 0; k < 3; ++k) vt[i-1][k] = -vt[i-1][k];
    }
  }
  for (int i = 1; i <= 2; ++i) {
    int isub = 1; float smn = D_(1);
    for (int j = 2; j <= 4-i; ++j) {
      if (D_(j) <= smn) { isub = j; smn = D_(j); }
    }
    if (isub != 4-i) {
      D_(isub) = D_(4-i); D_(4-i) = smn;
#pragma unroll
      for (int k = 0; k < 3; ++k) { float tq = vt[isub-1][k]; vt[isub-1][k] = vt[4-i-1][k]; vt[4-i-1][k] = tq; }
#pragma unroll
      for (int k = 0; k < 3; ++k) { float tq = u[k][isub-1]; u[k][isub-1] = u[k][4-i-1]; u[k][4-i-1] = tq; }
    }
  }
}

__device__ void svd3_gesdd(const float Ain[3][3], float u[3][3], float vt[3][3]) {
  float a[3][3];
#pragma unroll
  for (int i = 0; i < 3; ++i)
#pragma unroll
    for (int j = 0; j < 3; ++j) a[i][j] = Ain[i][j];

  float d[3], e[2];
  float tq0 = 0.f, tq1 = 0.f, tp0 = 0.f;
  float v0a = 0.f, v0b = 0.f, v1a = 0.f, p0a = 0.f;

  {
    float alpha = a[0][0];
    float xn = sqrtf(a[1][0]*a[1][0] + a[2][0]*a[2][0]);
    if (xn == 0.0f) { tq0 = 0.0f; d[0] = alpha; }
    else {
      float beta = -copysignf(sqrtf(alpha*alpha + xn*xn), alpha);
      tq0 = (beta - alpha)/beta;
      float sc = 1.0f/(alpha - beta);
      v0a = a[1][0]*sc; v0b = a[2][0]*sc;
      d[0] = beta;
    }
#pragma unroll
    for (int j = 1; j < 3; ++j) {
      float w = (a[0][j] + v0a*a[1][j] + v0b*a[2][j])*tq0;
      a[0][j] -= w; a[1][j] -= w*v0a; a[2][j] -= w*v0b;
    }
  }
  {
    float alpha = a[0][1];
    float xn = fabsf(a[0][2]);
    if (xn == 0.0f) { tp0 = 0.0f; e[0] = alpha; }
    else {
      float beta = -copysignf(sqrtf(alpha*alpha + xn*xn), alpha);
      tp0 = (beta - alpha)/beta;
      p0a = a[0][2]/(alpha - beta);
      e[0] = beta;
    }
#pragma unroll
    for (int i = 1; i < 3; ++i) {
      float w = (a[i][1] + p0a*a[i][2])*tp0;
      a[i][1] -= w; a[i][2] -= w*p0a;
    }
  }
  {
    float alpha = a[1][1];
    float xn = fabsf(a[2][1]);
    if (xn == 0.0f) { tq1 = 0.0f; d[1] = alpha; }
    else {
      float beta = -copysignf(sqrtf(alpha*alpha + xn*xn), alpha);
      tq1 = (beta - alpha)/beta;
      v1a = a[2][1]/(alpha - beta);
      d[1] = beta;
    }
    float w = (a[1][2] + v1a*a[2][2])*tq1;
    a[1][2] -= w; a[2][2] -= w*v1a;
  }
  e[1] = a[1][2];
  d[2] = a[2][2];

  float ub[3][3] = {{1,0,0},{0,1,0},{0,0,1}};
  float vb[3][3] = {{1,0,0},{0,1,0},{0,0,1}};
  sbdsqr3(d, e, ub, vb);

#pragma unroll
  for (int j = 0; j < 3; ++j) {
    float w = (ub[1][j] + v1a*ub[2][j])*tq1;
    ub[1][j] -= w; ub[2][j] -= w*v1a;
  }
#pragma unroll
  for (int j = 0; j < 3; ++j) {
    float w = (ub[0][j] + v0a*ub[1][j] + v0b*ub[2][j])*tq0;
    ub[0][j] -= w; ub[1][j] -= w*v0a; ub[2][j] -= w*v0b;
  }
#pragma unroll
  for (int i = 0; i < 3; ++i) {
    float w = (vb[i][1] + p0a*vb[i][2])*tp0;
    vb[i][1] -= w; vb[i][2] -= w*p0a;
  }
#pragma unroll
  for (int i = 0; i < 3; ++i)
#pragma unroll
    for (int j = 0; j < 3; ++j) { u[i][j] = ub[i][j]; vt[i][j] = vb[i][j]; }
}

// =============================================================================
// bf16 helpers (RNE, manual)
// =============================================================================
__device__ __forceinline__ unsigned short f2bf(float x) {
  unsigned int u = __float_as_uint(x);
  unsigned int r = (u + 0x7FFFu + ((u >> 16) & 1u)) >> 16;
  return (unsigned short)r;
}
__device__ __forceinline__ float bf2f(unsigned short h) {
  return __uint_as_float(((unsigned int)h) << 16);
}

// =============================================================================
// Kernel 0: pack.
//   Qp row (64B): [qh(16) | ql(16)]  with q pre-scaled by 0.25*log2(e)
//   Kp row (64B): [kh(16) | kl(16)]
//   Vp row (16B): float4 {v0, v1, v2, 0}
// Fragments (16x16x32 MFMA, lane = (ll=row/col, lg)):
//   a1  = Kp row @ byte lg*16            -> A1 = [kh|kl]
//   a2  = (lg<2) ? a1 : 0                -> A2 = [kh|0]
//   bq1 = Qp row @ byte (lg&1)*16        -> B1 = [qh|qh]
//   bq2 = (lg<2) ? Qp row @ 32+lg*16 : 0 -> B2 = [ql|0]
//   A1*B1 + A2*B2 = kh*qh + kl*qh + kh*ql ~= k*q  (residual kl*ql ~ 2^-16 rel)
// =============================================================================
__global__ __launch_bounds__(256)
void pack_kernel(const float* __restrict__ srcE, const float* __restrict__ tgtE,
                 const float* __restrict__ tgt,
                 unsigned short* __restrict__ Qp, unsigned short* __restrict__ Kp,
                 float4* __restrict__ Vp) {
  const int g = blockIdx.x*256 + threadIdx.x;   // 32768 = 16*2048
  const int b = g >> 11, n = g & 2047;
  const float* qs = srcE + (size_t)b*16*2048 + n;
  const float* ks = tgtE + (size_t)b*16*2048 + n;
  const float QSCALE = 0.25f * 1.44269504088896340736f;  // fold 1/4 and 1/ln2

  unsigned short qrow[32], krow[32];
#pragma unroll
  for (int dd = 0; dd < 16; ++dd) {
    float q = qs[dd*2048] * QSCALE;
    unsigned short qh = f2bf(q);
    qrow[dd] = qh; qrow[16+dd] = f2bf(q - bf2f(qh));
    float k = ks[dd*2048];
    unsigned short kh = f2bf(k);
    krow[dd] = kh; krow[16+dd] = f2bf(k - bf2f(kh));
  }
  uint4* qdst = (uint4*)(Qp + (size_t)g*32);
  uint4* kdst = (uint4*)(Kp + (size_t)g*32);
#pragma unroll
  for (int i = 0; i < 4; ++i) { qdst[i] = ((uint4*)qrow)[i]; kdst[i] = ((uint4*)krow)[i]; }

  const float* vp = tgt + (size_t)b*3*2048 + n;
  Vp[g] = make_float4(vp[0], vp[2048], vp[4096], 0.f);
}

// =============================================================================
// Kernel 1: MFMA flash attention + per-(b,ntile64) partial stats.
// grid = 512: bid = nt*16 + b  (=> bid%8 == b%8: one XCD's L2 holds 2 batches).
// block = 512 (8 waves). Each block: 64 n (4 MFMA n-tiles), ALL 2048 m.
// Wave w handles m-tiles w, w+8, ... (16 of 128). NO LDS staging, NO barriers
// in the main loop: A-frags straight from L2, V broadcast loads, Q in regs.
// =============================================================================
__global__ __launch_bounds__(512, 4)
void corr_kernel(const unsigned short* __restrict__ Qp, const unsigned short* __restrict__ Kp,
                 const float4* __restrict__ Vp, const float* __restrict__ src,
                 float* __restrict__ ws) {
  const int bid = blockIdx.x;
  const int b   = bid & 15;
  const int nt  = bid >> 4;          // 0..31, 64 n each
  const int tid = threadIdx.x;
  const int w   = tid >> 6;
  const int L   = tid & 63;
  const int lg  = L >> 4;
  const int ll  = L & 15;

  __shared__ __align__(16) float4 partial[8][64];   // 8 KB

  const unsigned short* Qb = Qp + (size_t)b*2048*32;
  const unsigned short* Kb = Kp + (size_t)b*2048*32;
  const float4* Vb = Vp + (size_t)b*2048;

  // ---- Q-fragments for this block's 4 n-tiles (registers) ----
  bf16x8 bq1[4], bq2[4];
  const bf16x8 zero8 = {0,0,0,0,0,0,0,0};
#pragma unroll
  for (int t2 = 0; t2 < 4; ++t2) {
    const unsigned short* qr = Qb + (size_t)(nt*64 + t2*16 + ll)*32;
    bq1[t2] = *(const bf16x8*)(qr + (lg & 1)*8);
    bf16x8 lo = *(const bf16x8*)(qr + 16 + (lg & 1)*8);
    bq2[t2] = (lg < 2) ? lo : zero8;
  }

  f32x4 acc[4];
#pragma unroll
  for (int t2 = 0; t2 < 4; ++t2) acc[t2] = (f32x4){0.f, 0.f, 0.f, 0.f};

  for (int mt = w; mt < 128; mt += 8) {
    const unsigned short* ar = Kb + (size_t)(mt*16 + ll)*32;
    bf16x8 a1 = *(const bf16x8*)(ar + lg*8);
    bf16x8 a2 = (lg < 2) ? a1 : zero8;
    const int vr = mt*16 + lg*4;
    float4 v0 = Vb[vr + 0];
    float4 v1 = Vb[vr + 1];
    float4 v2 = Vb[vr + 2];
    float4 v3 = Vb[vr + 3];
#pragma unroll
    for (int t2 = 0; t2 < 4; ++t2) {
      f32x4 c = (f32x4){0.f, 0.f, 0.f, 0.f};
      c = __builtin_amdgcn_mfma_f32_16x16x32_bf16(a1, bq1[t2], c, 0, 0, 0);
      c = __builtin_amdgcn_mfma_f32_16x16x32_bf16(a2, bq2[t2], c, 0, 0, 0);
      // C/D: col n = ll, row m = mt*16 + lg*4 + r
      float e0 = __builtin_amdgcn_exp2f(c.x);
      float e1 = __builtin_amdgcn_exp2f(c.y);
      float e2 = __builtin_amdgcn_exp2f(c.z);
      float e3 = __builtin_amdgcn_exp2f(c.w);
      acc[t2].x += (e0 + e1) + (e2 + e3);
      acc[t2].y += e0*v0.x + e1*v1.x + e2*v2.x + e3*v3.x;
      acc[t2].z += e0*v0.y + e1*v1.y + e2*v2.y + e3*v3.y;
      acc[t2].w += e0*v0.z + e1*v1.z + e2*v2.z + e3*v3.z;
    }
  }

  // ---- reduce across the 4 lane-groups ----
#pragma unroll
  for (int t2 = 0; t2 < 4; ++t2) {
    float x = acc[t2].x, y = acc[t2].y, z = acc[t2].z, ww = acc[t2].w;
    x += __shfl_xor(x, 16); x += __shfl_xor(x, 32);
    y += __shfl_xor(y, 16); y += __shfl_xor(y, 32);
    z += __shfl_xor(z, 16); z += __shfl_xor(z, 32);
    ww += __shfl_xor(ww, 16); ww += __shfl_xor(ww, 32);
    acc[t2] = (f32x4){x, y, z, ww};
  }
  if (lg == 0) {
#pragma unroll
    for (int t2 = 0; t2 < 4; ++t2)
      partial[w][t2*16 + ll] = make_float4(acc[t2].x, acc[t2].y, acc[t2].z, acc[t2].w);
  }
  __syncthreads();

  // ---- per-n finish + 15-value single-wave reduction (wave 0 only) ----
  if (tid < 64) {
    float4 s4 = make_float4(0.f, 0.f, 0.f, 0.f);
#pragma unroll
    for (int w2 = 0; w2 < 8; ++w2) {
      float4 p = partial[w2][tid];
      s4.x += p.x; s4.y += p.y; s4.z += p.z; s4.w += p.w;
    }
    float inv = 1.0f / s4.x;
    float c0 = s4.y*inv, c1 = s4.z*inv, c2 = s4.w*inv;
    const int n = nt*64 + tid;
    const float* sp = src + (size_t)b*3*2048;
    float s0v = sp[n], s1v = sp[2048+n], s2v = sp[4096+n];
    float vals[15] = { c0, c1, c2, s0v, s1v, s2v,
                       s0v*c0, s0v*c1, s0v*c2,
                       s1v*c0, s1v*c1, s1v*c2,
                       s2v*c0, s2v*c1, s2v*c2 };
#pragma unroll
    for (int k = 0; k < 15; ++k) {
      float v = vals[k];
      v += __shfl_xor(v, 1);  v += __shfl_xor(v, 2);  v += __shfl_xor(v, 4);
      v += __shfl_xor(v, 8);  v += __shfl_xor(v, 16); v += __shfl_xor(v, 32);
      vals[k] = v;
    }
    if (tid == 0) {
#pragma unroll
      for (int k = 0; k < 15; ++k) ws[bid*16 + k] = vals[k];
    }
  }
}

// =============================================================================
// Kernel 2: ONE block, 16 waves; wave w = batch w. Lane 0 runs the
// LAPACK-faithful SVD (i-cache shared, waves latency-hide each other).
// =============================================================================
__global__ __launch_bounds__(1024)
void finalize_kernel(const float* __restrict__ ws, float* __restrict__ out) {
  const int b = threadIdx.x >> 6;
  const int L = threadIdx.x & 63;

  float a = 0.0f;
  if (L < 15) {
#pragma unroll
    for (int ntile = 0; ntile < 32; ++ntile)
      a += ws[(ntile*16 + b)*16 + L];
  }
  float acc[15];
#pragma unroll
  for (int k = 0; k < 15; ++k) acc[k] = __shfl(a, k);

  if (L == 0) {
    const float invN = 1.0f/2048.0f;
    float Sc[3] = {acc[0], acc[1], acc[2]};
    float Ss[3] = {acc[3], acc[4], acc[5]};
    float cm[3] = {Sc[0]*invN, Sc[1]*invN, Sc[2]*invN};
    float sm[3] = {Ss[0]*invN, Ss[1]*invN, Ss[2]*invN};

    float A[3][3];
#pragma unroll
    for (int i = 0; i < 3; ++i)
#pragma unroll
      for (int j = 0; j < 3; ++j)
        A[i][j] = acc[6 + i*3 + j] - Ss[i]*cm[j];

    float u[3][3], vt[3][3];
    svd3_gesdd(A, u, vt);

    float R[3][3];
#pragma unroll
    for (int i = 0; i < 3; ++i)
#pragma unroll
      for (int k = 0; k < 3; ++k)
        R[i][k] = vt[i][0]*u[k][0] + vt[i][1]*u[k][1] + vt[i][2]*u[k][2];

    float det = R[0][0]*(R[1][1]*R[2][2] - R[1][2]*R[2][1])
              - R[0][1]*(R[1][0]*R[2][2] - R[1][2]*R[2][0])
              + R[0][2]*(R[1][0]*R[2][1] - R[1][1]*R[2][0]);

    if (det < 0.0f) {
#pragma unroll
      for (int i = 0; i < 3; ++i)
#pragma unroll
        for (int k = 0; k < 3; ++k)
          R[i][k] -= 2.0f*vt[i][2]*u[k][2];
    }

    float tv[3];
#pragma unroll
    for (int i = 0; i < 3; ++i)
      tv[i] = -(R[i][0]*sm[0] + R[i][1]*sm[1] + R[i][2]*sm[2]) + cm[i];

#pragma unroll
    for (int i = 0; i < 3; ++i)
#pragma unroll
      for (int j = 0; j < 3; ++j)
        out[b*9 + i*3 + j] = R[i][j];
#pragma unroll
    for (int i = 0; i < 3; ++i)
      out[144 + b*3 + i] = tv[i];
  }
}

extern "C" void kernel_launch(void* const* d_in, const int* in_sizes, int n_in,
                              void* d_out, int out_size, void* d_ws, size_t ws_size,
                              hipStream_t stream) {
  const float* srcE = (const float*)d_in[0];
  const float* tgtE = (const float*)d_in[1];
  const float* src  = (const float*)d_in[2];
  const float* tgt  = (const float*)d_in[3];
  float* out = (float*)d_out;

  // ws layout: [0,32KB) partials | Qp 2MB | Kp 2MB | Vp 512KB  (total ~4.53MB)
  float* part = (float*)d_ws;
  unsigned short* Qp = (unsigned short*)((char*)d_ws + 32768);
  unsigned short* Kp = (unsigned short*)((char*)d_ws + 32768 + (size_t)16*2048*32*2);
  float4* Vp = (float4*)((char*)d_ws + 32768 + (size_t)2*16*2048*32*2);

  hipLaunchKernelGGL(pack_kernel, dim3(128), dim3(256), 0, stream, srcE, tgtE, tgt, Qp, Kp, Vp);
  hipLaunchKernelGGL(corr_kernel, dim3(512), dim3(512), 0, stream, Qp, Kp, Vp, src, part);
  hipLaunchKernelGGL(finalize_kernel, dim3(1), dim3(1024), 0, stream, part, out);
}

// Round 4
// 57.841 us; speedup vs baseline: 1.7356x; 1.0011x over previous
//
#include <hip/hip_runtime.h>
#include <math.h>

// LAPACK >= 3.10 slartg convention (c >= 0). Flip to 0 to emulate <= 3.9.
#define NEW_SLARTG 1

typedef __attribute__((ext_vector_type(8))) short bf16x8;
typedef __attribute__((ext_vector_type(4))) float f32x4;

// =============================================================================
// LAPACK sgesdd emulation for 3x3 (f32), faithful sign conventions. (UNCHANGED)
// =============================================================================

__device__ __forceinline__ void slartg_f(float f, float g, float& c, float& s, float& r) {
#if NEW_SLARTG
  if (g == 0.0f) { c = 1.0f; s = 0.0f; r = f; }
  else if (f == 0.0f) { c = 0.0f; s = copysignf(1.0f, g); r = fabsf(g); }
  else {
    float d = sqrtf(f*f + g*g);
    c = fabsf(f) / d;
    r = copysignf(d, f);
    s = g / r;
  }
#else
  if (g == 0.0f) { c = 1.0f; s = 0.0f; r = f; }
  else if (f == 0.0f) { c = 0.0f; s = 1.0f; r = g; }
  else {
    float d = sqrtf(f*f + g*g);
    c = f / d; s = g / d; r = d;
    if (fabsf(f) > fabsf(g) && c < 0.0f) { c = -c; s = -s; r = -r; }
  }
#endif
}

__device__ __forceinline__ void slas2_f(float f, float g, float h, float& ssmin, float& ssmax) {
  float fa = fabsf(f), ga = fabsf(g), ha = fabsf(h);
  float fhmn = fminf(fa, ha), fhmx = fmaxf(fa, ha);
  if (fhmn == 0.0f) {
    ssmin = 0.0f;
    if (fhmx == 0.0f) ssmax = ga;
    else {
      float mn = fminf(fhmx, ga), mx = fmaxf(fhmx, ga);
      float qq = mn / mx;
      ssmax = mx * sqrtf(1.0f + qq*qq);
    }
  } else {
    if (ga < fhmx) {
      float as_ = 1.0f + fhmn/fhmx;
      float at_ = (fhmx - fhmn)/fhmx;
      float au_ = ga/fhmx; au_ = au_*au_;
      float c = 2.0f/(sqrtf(as_*as_ + au_) + sqrtf(at_*at_ + au_));
      ssmin = fhmn*c;
      ssmax = fhmx/c;
    } else {
      float au_ = fhmx/ga;
      if (au_ == 0.0f) {
        ssmin = (fhmn*fhmx)/ga;
        ssmax = ga;
      } else {
        float as_ = 1.0f + fhmn/fhmx;
        float at_ = (fhmx - fhmn)/fhmx;
        float t1 = as_*au_, t2 = at_*au_;
        float c = 1.0f/(sqrtf(1.0f + t1*t1) + sqrtf(1.0f + t2*t2));
        ssmin = (fhmn*c)*au_;
        ssmin = ssmin + ssmin;
        ssmax = ga/(c + c);
      }
    }
  }
}

__device__ void slasv2_f(float f, float g, float h,
                         float& ssmin, float& ssmax,
                         float& snr, float& csr, float& snl, float& csl) {
  const float eps = 5.9604645e-08f;
  float ft = f, fa = fabsf(f), ht = h, ha = fabsf(h);
  int pmax = 1;
  bool swap_ = (ha > fa);
  if (swap_) {
    pmax = 3;
    float tq = ft; ft = ht; ht = tq;
    tq = fa; fa = ha; ha = tq;
  }
  float gt = g, ga = fabsf(g);
  float clt = 0.f, crt = 0.f, slt = 0.f, srt = 0.f;
  if (ga == 0.0f) {
    ssmin = ha; ssmax = fa;
    clt = 1.0f; crt = 1.0f; slt = 0.0f; srt = 0.0f;
  } else {
    bool gasmal = true;
    if (ga > fa) {
      pmax = 2;
      if ((fa/ga) < eps) {
        gasmal = false;
        ssmax = ga;
        ssmin = (ha > 1.0f) ? (fa/(ga/ha)) : ((fa/ga)*ha);
        clt = 1.0f; slt = ht/gt; srt = 1.0f; crt = ft/gt;
      }
    }
    if (gasmal) {
      float dd = fa - ha;
      float l = (dd == fa) ? 1.0f : (dd/fa);
      float mr = gt/ft;
      float t = 2.0f - l;
      float mm2 = mr*mr, tt = t*t;
      float s_ = sqrtf(tt + mm2);
      float r_ = (l == 0.0f) ? fabsf(mr) : sqrtf(l*l + mm2);
      float a_ = 0.5f*(s_ + r_);
      ssmin = ha/a_;
      ssmax = fa*a_;
      if (mm2 == 0.0f) {
        if (l == 0.0f) t = copysignf(2.0f, ft)*copysignf(1.0f, gt);
        else t = gt/copysignf(dd, ft) + mr/t;
      } else {
        t = (mr/(s_ + t) + mr/(r_ + l))*(1.0f + a_);
      }
      float l2 = sqrtf(t*t + 4.0f);
      crt = 2.0f/l2;
      srt = t/l2;
      clt = (crt + srt*mr)/a_;
      slt = (ht/ft)*srt/a_;
    }
  }
  if (swap_) { csl = srt; snl = crt; csr = slt; snr = clt; }
  else       { csl = clt; snl = slt; csr = crt; snr = srt; }
  float tsign = 0.f;
  if (pmax == 1) tsign = copysignf(1.0f, csr)*copysignf(1.0f, csl)*copysignf(1.0f, f);
  if (pmax == 2) tsign = copysignf(1.0f, snr)*copysignf(1.0f, csl)*copysignf(1.0f, g);
  if (pmax == 3) tsign = copysignf(1.0f, snr)*copysignf(1.0f, snl)*copysignf(1.0f, h);
  ssmax = copysignf(ssmax, tsign);
  ssmin = copysignf(ssmin, tsign*copysignf(1.0f, f)*copysignf(1.0f, h));
}

__device__ __forceinline__ void rot_rows3(float mt[3][3], int r1, int r2, float c, float s) {
#pragma unroll
  for (int k = 0; k < 3; ++k) {
    float x = mt[r1][k], y = mt[r2][k];
    mt[r1][k] = c*x + s*y;
    mt[r2][k] = c*y - s*x;
  }
}
__device__ __forceinline__ void rot_cols3(float mt[3][3], int c1_, int c2_, float c, float s) {
#pragma unroll
  for (int k = 0; k < 3; ++k) {
    float x = mt[k][c1_], y = mt[k][c2_];
    mt[k][c1_] = c*x + s*y;
    mt[k][c2_] = c*y - s*x;
  }
}

#define D_(i) d[(i)-1]
#define E_(i) e[(i)-1]

__device__ void sbdsqr3(float* d, float* e, float u[3][3], float vt[3][3]) {
  const float eps  = 5.9604645e-08f;
  const float unfl = 1.17549435e-38f;
  const float tol  = 10.0f*eps;

  float sminoa = fabsf(d[0]);
  if (sminoa != 0.0f) {
    float mu = sminoa;
    mu = fabsf(d[1])*(mu/(mu + fabsf(e[0])));
    sminoa = fminf(sminoa, mu);
    if (sminoa != 0.0f) {
      mu = fabsf(d[2])*(mu/(mu + fabsf(e[1])));
      sminoa = fminf(sminoa, mu);
    }
  }
  sminoa = sminoa / sqrtf(3.0f);
  float thresh = fmaxf(tol*sminoa, 54.0f*unfl);

  int m = 3, oldll = -1, oldm = -1, idir = 0;
  int guard = 0;
  while (m > 1 && ++guard < 200) {
    float smax = fabsf(D_(m));
    int ll = 1; bool split = false;
    for (int lll = 1; lll <= m-1; ++lll) {
      int l2 = m - lll;
      float abss = fabsf(D_(l2)), abse = fabsf(E_(l2));
      if (abse <= thresh) { ll = l2; split = true; break; }
      smax = fmaxf(smax, fmaxf(abss, abse));
    }
    if (split) {
      E_(ll) = 0.0f;
      if (ll == m-1) { m = m - 1; continue; }
      ll = ll + 1;
    } else ll = 1;

    if (ll == m-1) {
      float sigmn, sigmx, sinr, cosr, sinl, cosl;
      slasv2_f(D_(m-1), E_(m-1), D_(m), sigmn, sigmx, sinr, cosr, sinl, cosl);
      D_(m-1) = sigmx; D_(m) = sigmn; E_(m-1) = 0.0f;
      rot_rows3(vt, m-2, m-1, cosr, sinr);
      rot_cols3(u,  m-2, m-1, cosl, sinl);
      m -= 2; continue;
    }

    if (ll > oldm || m < oldll)
      idir = (fabsf(D_(ll)) >= fabsf(D_(m))) ? 1 : 2;

    float sminl = 0.0f;
    bool deflated = false;
    if (idir == 1) {
      if (fabsf(E_(m-1)) <= tol*fabsf(D_(m))) { E_(m-1) = 0.0f; continue; }
      float mu = fabsf(D_(ll)); sminl = mu;
      for (int lll = ll; lll <= m-1; ++lll) {
        if (fabsf(E_(lll)) <= tol*mu) { E_(lll) = 0.0f; deflated = true; break; }
        mu = fabsf(D_(lll+1))*(mu/(mu + fabsf(E_(lll))));
        sminl = fminf(sminl, mu);
      }
    } else {
      if (fabsf(E_(ll)) <= tol*fabsf(D_(ll))) { E_(ll) = 0.0f; continue; }
      float mu = fabsf(D_(m)); sminl = mu;
      for (int lll = m-1; lll >= ll; --lll) {
        if (fabsf(E_(lll)) <= tol*mu) { E_(lll) = 0.0f; deflated = true; break; }
        mu = fabsf(D_(lll))*(mu/(mu + fabsf(E_(lll))));
        sminl = fminf(sminl, mu);
      }
    }
    if (deflated) continue;
    oldll = ll; oldm = m;

    float shift = 0.0f, rdum;
    if (!(3.0f*tol*(sminl/smax) <= fmaxf(eps, 0.01f*tol))) {
      float sll;
      if (idir == 1) { sll = fabsf(D_(ll)); slas2_f(D_(m-1), E_(m-1), D_(m), shift, rdum); }
      else           { sll = fabsf(D_(m));  slas2_f(D_(ll), E_(ll), D_(ll+1), shift, rdum); }
      if (sll > 0.0f) { float qq = shift/sll; if (qq*qq < eps) shift = 0.0f; }
    }

    if (shift == 0.0f) {
      if (idir == 1) {
        float cs = 1.0f, oldcs = 1.0f, sn = 0.0f, oldsn = 0.0f, r;
        float c1[2], s1[2], c2[2], s2[2];
        int k = 0;
        for (int i = ll; i <= m-1; ++i, ++k) {
          float fin = D_(i)*cs;
          slartg_f(fin, E_(i), cs, sn, r);
          if (i > ll) E_(i-1) = oldsn*r;
          float f2 = oldcs*r, g2 = D_(i+1)*sn;
          slartg_f(f2, g2, oldcs, oldsn, D_(i));
          c1[k] = cs; s1[k] = sn; c2[k] = oldcs; s2[k] = oldsn;
        }
        float h = D_(m)*cs;
        D_(m) = h*oldcs;
        E_(m-1) = h*oldsn;
        k = 0;
        for (int i = ll; i <= m-1; ++i, ++k) rot_rows3(vt, i-1, i, c1[k], s1[k]);
        k = 0;
        for (int i = ll; i <= m-1; ++i, ++k) rot_cols3(u, i-1, i, c2[k], s2[k]);
        if (fabsf(E_(m-1)) <= thresh) E_(m-1) = 0.0f;
      } else {
        float cs = 1.0f, oldcs = 1.0f, sn = 0.0f, oldsn = 0.0f, r;
        float c1[2], s1[2], c2[2], s2[2];
        for (int i = m; i >= ll+1; --i) {
          float fin = D_(i)*cs;
          slartg_f(fin, E_(i-1), cs, sn, r);
          if (i < m) E_(i) = oldsn*r;
          float f2 = oldcs*r, g2 = D_(i-1)*sn;
          slartg_f(f2, g2, oldcs, oldsn, D_(i));
          int slot = i - ll;
          c1[slot-1] = cs; s1[slot-1] = -sn; c2[slot-1] = oldcs; s2[slot-1] = -oldsn;
        }
        float h = D_(ll)*cs;
        D_(ll) = h*oldcs;
        E_(ll) = h*oldsn;
        for (int j = m-ll; j >= 1; --j) rot_rows3(vt, ll+j-2, ll+j-1, c2[j-1], s2[j-1]);
        for (int j = m-ll; j >= 1; --j) rot_cols3(u,  ll+j-2, ll+j-1, c1[j-1], s1[j-1]);
        if (fabsf(E_(ll)) <= thresh) E_(ll) = 0.0f;
      }
    } else {
      if (idir == 1) {
        float f = (fabsf(D_(ll)) - shift)*(copysignf(1.0f, D_(ll)) + shift/D_(ll));
        float g = E_(ll);
        float cr, sr, cl, sl, r;
        float c1[2], s1[2], c2[2], s2[2];
        int k = 0;
        for (int i = ll; i <= m-1; ++i, ++k) {
          slartg_f(f, g, cr, sr, r);
          if (i > ll) E_(i-1) = r;
          f = cr*D_(i) + sr*E_(i);
          E_(i) = cr*E_(i) - sr*D_(i);
          g = sr*D_(i+1);
          D_(i+1) = cr*D_(i+1);
          slartg_f(f, g, cl, sl, r);
          D_(i) = r;
          f = cl*E_(i) + sl*D_(i+1);
          D_(i+1) = cl*D_(i+1) - sl*E_(i);
          if (i < m-1) { g = sl*E_(i+1); E_(i+1) = cl*E_(i+1); }
          c1[k] = cr; s1[k] = sr; c2[k] = cl; s2[k] = sl;
        }
        E_(m-1) = f;
        k = 0;
        for (int i = ll; i <= m-1; ++i, ++k) rot_rows3(vt, i-1, i, c1[k], s1[k]);
        k = 0;
        for (int i = ll; i <= m-1; ++i, ++k) rot_cols3(u, i-1, i, c2[k], s2[k]);
        if (fabsf(E_(m-1)) <= thresh) E_(m-1) = 0.0f;
      } else {
        float f = (fabsf(D_(m)) - shift)*(copysignf(1.0f, D_(m)) + shift/D_(m));
        float g = E_(m-1);
        float cr, sr, cl, sl, r;
        float c1[2], s1[2], c2[2], s2[2];
        for (int i = m; i >= ll+1; --i) {
          slartg_f(f, g, cr, sr, r);
          if (i < m) E_(i) = r;
          f = cr*D_(i) + sr*E_(i-1);
          E_(i-1) = cr*E_(i-1) - sr*D_(i);
          g = sr*D_(i-1);
          D_(i-1) = cr*D_(i-1);
          slartg_f(f, g, cl, sl, r);
          D_(i) = r;
          f = cl*E_(i-1) + sl*D_(i-1);
          D_(i-1) = cl*D_(i-1) - sl*E_(i-1);
          if (i > ll+1) { g = sl*E_(i-2); E_(i-2) = cl*E_(i-2); }
          int slot = i - ll;
          c1[slot-1] = cr; s1[slot-1] = -sr; c2[slot-1] = cl; s2[slot-1] = -sl;
        }
        E_(ll) = f;
        if (fabsf(E_(ll)) <= thresh) E_(ll) = 0.0f;
        for (int j = m-ll; j >= 1; --j) rot_rows3(vt, ll+j-2, ll+j-1, c2[j-1], s2[j-1]);
        for (int j = m-ll; j >= 1; --j) rot_cols3(u,  ll+j-2, ll+j-1, c1[j-1], s1[j-1]);
      }
    }
  }

  for (int i = 1; i <= 3; ++i) {
    if (D_(i) < 0.0f) {
      D_(i) = -D_(i);
#pragma unroll
      for (int k = 0; k < 3; ++k) vt[i-1][k] = -vt[i-1][k];
    }
  }
  for (int i = 1; i <= 2; ++i) {
    int isub = 1; float smn = D_(1);
    for (int j = 2; j <= 4-i; ++j) {
      if (D_(j) <= smn) { isub = j; smn = D_(j); }
    }
    if (isub != 4-i) {
      D_(isub) = D_(4-i); D_(4-i) = smn;
#pragma unroll
      for (int k = 0; k < 3; ++k) { float tq = vt[isub-1][k]; vt[isub-1][k] = vt[4-i-1][k]; vt[4-i-1][k] = tq; }
#pragma unroll
      for (int k = 0; k < 3; ++k) { float tq = u[k][isub-1]; u[k][isub-1] = u[k][4-i-1]; u[k][4-i-1] = tq; }
    }
  }
}

__device__ void svd3_gesdd(const float Ain[3][3], float u[3][3], float vt[3][3]) {
  float a[3][3];
#pragma unroll
  for (int i = 0; i < 3; ++i)
#pragma unroll
    for (int j = 0; j < 3; ++j) a[i][j] = Ain[i][j];

  float d[3], e[2];
  float tq0 = 0.f, tq1 = 0.f, tp0 = 0.f;
  float v0a = 0.f, v0b = 0.f, v1a = 0.f, p0a = 0.f;

  {
    float alpha = a[0][0];
    float xn = sqrtf(a[1][0]*a[1][0] + a[2][0]*a[2][0]);
    if (xn == 0.0f) { tq0 = 0.0f; d[0] = alpha; }
    else {
      float beta = -copysignf(sqrtf(alpha*alpha + xn*xn), alpha);
      tq0 = (beta - alpha)/beta;
      float sc = 1.0f/(alpha - beta);
      v0a = a[1][0]*sc; v0b = a[2][0]*sc;
      d[0] = beta;
    }
#pragma unroll
    for (int j = 1; j < 3; ++j) {
      float w = (a[0][j] + v0a*a[1][j] + v0b*a[2][j])*tq0;
      a[0][j] -= w; a[1][j] -= w*v0a; a[2][j] -= w*v0b;
    }
  }
  {
    float alpha = a[0][1];
    float xn = fabsf(a[0][2]);
    if (xn == 0.0f) { tp0 = 0.0f; e[0] = alpha; }
    else {
      float beta = -copysignf(sqrtf(alpha*alpha + xn*xn), alpha);
      tp0 = (beta - alpha)/beta;
      p0a = a[0][2]/(alpha - beta);
      e[0] = beta;
    }
#pragma unroll
    for (int i = 1; i < 3; ++i) {
      float w = (a[i][1] + p0a*a[i][2])*tp0;
      a[i][1] -= w; a[i][2] -= w*p0a;
    }
  }
  {
    float alpha = a[1][1];
    float xn = fabsf(a[2][1]);
    if (xn == 0.0f) { tq1 = 0.0f; d[1] = alpha; }
    else {
      float beta = -copysignf(sqrtf(alpha*alpha + xn*xn), alpha);
      tq1 = (beta - alpha)/beta;
      v1a = a[2][1]/(alpha - beta);
      d[1] = beta;
    }
    float w = (a[1][2] + v1a*a[2][2])*tq1;
    a[1][2] -= w; a[2][2] -= w*v1a;
  }
  e[1] = a[1][2];
  d[2] = a[2][2];

  float ub[3][3] = {{1,0,0},{0,1,0},{0,0,1}};
  float vb[3][3] = {{1,0,0},{0,1,0},{0,0,1}};
  sbdsqr3(d, e, ub, vb);

#pragma unroll
  for (int j = 0; j < 3; ++j) {
    float w = (ub[1][j] + v1a*ub[2][j])*tq1;
    ub[1][j] -= w; ub[2][j] -= w*v1a;
  }
#pragma unroll
  for (int j = 0; j < 3; ++j) {
    float w = (ub[0][j] + v0a*ub[1][j] + v0b*ub[2][j])*tq0;
    ub[0][j] -= w; ub[1][j] -= w*v0a; ub[2][j] -= w*v0b;
  }
#pragma unroll
  for (int i = 0; i < 3; ++i) {
    float w = (vb[i][1] + p0a*vb[i][2])*tp0;
    vb[i][1] -= w; vb[i][2] -= w*p0a;
  }
#pragma unroll
  for (int i = 0; i < 3; ++i)
#pragma unroll
    for (int j = 0; j < 3; ++j) { u[i][j] = ub[i][j]; vt[i][j] = vb[i][j]; }
}

// =============================================================================
// bf16 helpers (RNE, manual)
// =============================================================================
__device__ __forceinline__ unsigned short f2bf(float x) {
  unsigned int u = __float_as_uint(x);
  unsigned int r = (u + 0x7FFFu + ((u >> 16) & 1u)) >> 16;
  return (unsigned short)r;
}
__device__ __forceinline__ float bf2f(unsigned short h) {
  return __uint_as_float(((unsigned int)h) << 16);
}

// =============================================================================
// Kernel 0: pack.  Qp row: [qh(16)|ql(16)] (pre-scaled 0.25*log2e); Kp row:
// [kh(16)|kl(16)]; Vp row: float4. 256 blocks x 128 thr = 1 thread per (b,n).
// =============================================================================
__global__ __launch_bounds__(128)
void pack_kernel(const float* __restrict__ srcE, const float* __restrict__ tgtE,
                 const float* __restrict__ tgt,
                 unsigned short* __restrict__ Qp, unsigned short* __restrict__ Kp,
                 float4* __restrict__ Vp) {
  const int g = blockIdx.x*128 + threadIdx.x;   // 32768 = 16*2048
  const int b = g >> 11, n = g & 2047;
  const float* qs = srcE + (size_t)b*16*2048 + n;
  const float* ks = tgtE + (size_t)b*16*2048 + n;
  const float QSCALE = 0.25f * 1.44269504088896340736f;  // fold 1/4 and 1/ln2

  unsigned short qrow[32], krow[32];
#pragma unroll
  for (int dd = 0; dd < 16; ++dd) {
    float q = qs[dd*2048] * QSCALE;
    unsigned short qh = f2bf(q);
    qrow[dd] = qh; qrow[16+dd] = f2bf(q - bf2f(qh));
    float k = ks[dd*2048];
    unsigned short kh = f2bf(k);
    krow[dd] = kh; krow[16+dd] = f2bf(k - bf2f(kh));
  }
  uint4* qdst = (uint4*)(Qp + (size_t)g*32);
  uint4* kdst = (uint4*)(Kp + (size_t)g*32);
#pragma unroll
  for (int i = 0; i < 4; ++i) { qdst[i] = ((uint4*)qrow)[i]; kdst[i] = ((uint4*)krow)[i]; }

  const float* vp = tgt + (size_t)b*3*2048 + n;
  Vp[g] = make_float4(vp[0], vp[2048], vp[4096], 0.f);
}

// =============================================================================
// Kernel 1: MFMA flash attention + per-(b,ntile64) partial stats.
// grid = 512: bid = nt*16 + b (bid%8==b%8 -> one XCD's L2 holds 2 batches).
// block = 512 (8 waves), 64 n x 2048 m per block; wave w: m-tiles w,w+8,...
// SOFTWARE-PIPELINED: next m-tile's K-frag + V rows are loaded before the
// current tile's MFMA/exp/PV compute (hides ~200-400cy L2 latency).
// =============================================================================
__global__ __launch_bounds__(512, 4)
void corr_kernel(const unsigned short* __restrict__ Qp, const unsigned short* __restrict__ Kp,
                 const float4* __restrict__ Vp, const float* __restrict__ src,
                 float* __restrict__ ws) {
  const int bid = blockIdx.x;
  const int b   = bid & 15;
  const int nt  = bid >> 4;          // 0..31, 64 n each
  const int tid = threadIdx.x;
  const int w   = tid >> 6;
  const int L   = tid & 63;
  const int lg  = L >> 4;
  const int ll  = L & 15;

  __shared__ __align__(16) float4 partial[8][64];   // 8 KB

  const unsigned short* Qb = Qp + (size_t)b*2048*32;
  const unsigned short* Kb = Kp + (size_t)b*2048*32;
  const float4* Vb = Vp + (size_t)b*2048;

  // ---- Q-fragments for this block's 4 n-tiles (registers) ----
  bf16x8 bq1[4], bq2[4];
  const bf16x8 zero8 = {0,0,0,0,0,0,0,0};
#pragma unroll
  for (int t2 = 0; t2 < 4; ++t2) {
    const unsigned short* qr = Qb + (size_t)(nt*64 + t2*16 + ll)*32;
    bq1[t2] = *(const bf16x8*)(qr + (lg & 1)*8);
    bf16x8 lo = *(const bf16x8*)(qr + 16 + (lg & 1)*8);
    bq2[t2] = (lg < 2) ? lo : zero8;
  }

  f32x4 acc[4];
#pragma unroll
  for (int t2 = 0; t2 < 4; ++t2) acc[t2] = (f32x4){0.f, 0.f, 0.f, 0.f};

  // ---- software-pipelined m-loop ----
  bf16x8 a1c, a1n;
  float4 v0c, v1c, v2c, v3c, v0n, v1n, v2n, v3n;
  {
    const unsigned short* ar = Kb + (size_t)(w*16 + ll)*32;
    a1c = *(const bf16x8*)(ar + lg*8);
    const int vr = w*16 + lg*4;
    v0c = Vb[vr+0]; v1c = Vb[vr+1]; v2c = Vb[vr+2]; v3c = Vb[vr+3];
  }
  a1n = a1c; v0n = v0c; v1n = v1c; v2n = v2c; v3n = v3c;

  for (int mt = w; mt < 128; mt += 8) {
    const int mtn = mt + 8;
    if (mtn < 128) {                       // wave-uniform prefetch of next tile
      const unsigned short* arn = Kb + (size_t)(mtn*16 + ll)*32;
      a1n = *(const bf16x8*)(arn + lg*8);
      const int vrn = mtn*16 + lg*4;
      v0n = Vb[vrn+0]; v1n = Vb[vrn+1]; v2n = Vb[vrn+2]; v3n = Vb[vrn+3];
    }
    bf16x8 a2 = (lg < 2) ? a1c : zero8;
#pragma unroll
    for (int t2 = 0; t2 < 4; ++t2) {
      f32x4 c = (f32x4){0.f, 0.f, 0.f, 0.f};
      c = __builtin_amdgcn_mfma_f32_16x16x32_bf16(a1c, bq1[t2], c, 0, 0, 0);
      c = __builtin_amdgcn_mfma_f32_16x16x32_bf16(a2, bq2[t2], c, 0, 0, 0);
      // C/D: col n = ll, row m = mt*16 + lg*4 + r
      float e0 = __builtin_amdgcn_exp2f(c.x);
      float e1 = __builtin_amdgcn_exp2f(c.y);
      float e2 = __builtin_amdgcn_exp2f(c.z);
      float e3 = __builtin_amdgcn_exp2f(c.w);
      acc[t2].x += (e0 + e1) + (e2 + e3);
      acc[t2].y += e0*v0c.x + e1*v1c.x + e2*v2c.x + e3*v3c.x;
      acc[t2].z += e0*v0c.y + e1*v1c.y + e2*v2c.y + e3*v3c.y;
      acc[t2].w += e0*v0c.z + e1*v1c.z + e2*v2c.z + e3*v3c.z;
    }
    a1c = a1n; v0c = v0n; v1c = v1n; v2c = v2n; v3c = v3n;
  }

  // ---- reduce across the 4 lane-groups ----
#pragma unroll
  for (int t2 = 0; t2 < 4; ++t2) {
    float x = acc[t2].x, y = acc[t2].y, z = acc[t2].z, ww = acc[t2].w;
    x += __shfl_xor(x, 16); x += __shfl_xor(x, 32);
    y += __shfl_xor(y, 16); y += __shfl_xor(y, 32);
    z += __shfl_xor(z, 16); z += __shfl_xor(z, 32);
    ww += __shfl_xor(ww, 16); ww += __shfl_xor(ww, 32);
    acc[t2] = (f32x4){x, y, z, ww};
  }
  if (lg == 0) {
#pragma unroll
    for (int t2 = 0; t2 < 4; ++t2)
      partial[w][t2*16 + ll] = make_float4(acc[t2].x, acc[t2].y, acc[t2].z, acc[t2].w);
  }
  __syncthreads();

  // ---- per-n finish + 15-value single-wave reduction (wave 0 only) ----
  if (tid < 64) {
    float4 s4 = make_float4(0.f, 0.f, 0.f, 0.f);
#pragma unroll
    for (int w2 = 0; w2 < 8; ++w2) {
      float4 p = partial[w2][tid];
      s4.x += p.x; s4.y += p.y; s4.z += p.z; s4.w += p.w;
    }
    float inv = 1.0f / s4.x;
    float c0 = s4.y*inv, c1 = s4.z*inv, c2 = s4.w*inv;
    const int n = nt*64 + tid;
    const float* sp = src + (size_t)b*3*2048;
    float s0v = sp[n], s1v = sp[2048+n], s2v = sp[4096+n];
    float vals[15] = { c0, c1, c2, s0v, s1v, s2v,
                       s0v*c0, s0v*c1, s0v*c2,
                       s1v*c0, s1v*c1, s1v*c2,
                       s2v*c0, s2v*c1, s2v*c2 };
#pragma unroll
    for (int k = 0; k < 15; ++k) {
      float v = vals[k];
      v += __shfl_xor(v, 1);  v += __shfl_xor(v, 2);  v += __shfl_xor(v, 4);
      v += __shfl_xor(v, 8);  v += __shfl_xor(v, 16); v += __shfl_xor(v, 32);
      vals[k] = v;
    }
    if (tid == 0) {
#pragma unroll
      for (int k = 0; k < 15; ++k) ws[bid*16 + k] = vals[k];
    }
  }
}

// =============================================================================
// Kernel 2: ONE block, 16 waves; wave w = batch w; lane 0 runs the SVD.
// =============================================================================
__global__ __launch_bounds__(1024)
void finalize_kernel(const float* __restrict__ ws, float* __restrict__ out) {
  const int b = threadIdx.x >> 6;
  const int L = threadIdx.x & 63;

  float a = 0.0f;
  if (L < 15) {
#pragma unroll
    for (int ntile = 0; ntile < 32; ++ntile)
      a += ws[(ntile*16 + b)*16 + L];
  }
  float acc[15];
#pragma unroll
  for (int k = 0; k < 15; ++k) acc[k] = __shfl(a, k);

  if (L == 0) {
    const float invN = 1.0f/2048.0f;
    float Sc[3] = {acc[0], acc[1], acc[2]};
    float Ss[3] = {acc[3], acc[4], acc[5]};
    float cm[3] = {Sc[0]*invN, Sc[1]*invN, Sc[2]*invN};
    float sm[3] = {Ss[0]*invN, Ss[1]*invN, Ss[2]*invN};

    float A[3][3];
#pragma unroll
    for (int i = 0; i < 3; ++i)
#pragma unroll
      for (int j = 0; j < 3; ++j)
        A[i][j] = acc[6 + i*3 + j] - Ss[i]*cm[j];

    float u[3][3], vt[3][3];
    svd3_gesdd(A, u, vt);

    float R[3][3];
#pragma unroll
    for (int i = 0; i < 3; ++i)
#pragma unroll
      for (int k = 0; k < 3; ++k)
        R[i][k] = vt[i][0]*u[k][0] + vt[i][1]*u[k][1] + vt[i][2]*u[k][2];

    float det = R[0][0]*(R[1][1]*R[2][2] - R[1][2]*R[2][1])
              - R[0][1]*(R[1][0]*R[2][2] - R[1][2]*R[2][0])
              + R[0][2]*(R[1][0]*R[2][1] - R[1][1]*R[2][0]);

    if (det < 0.0f) {
#pragma unroll
      for (int i = 0; i < 3; ++i)
#pragma unroll
        for (int k = 0; k < 3; ++k)
          R[i][k] -= 2.0f*vt[i][2]*u[k][2];
    }

    float tv[3];
#pragma unroll
    for (int i = 0; i < 3; ++i)
      tv[i] = -(R[i][0]*sm[0] + R[i][1]*sm[1] + R[i][2]*sm[2]) + cm[i];

#pragma unroll
    for (int i = 0; i < 3; ++i)
#pragma unroll
      for (int j = 0; j < 3; ++j)
        out[b*9 + i*3 + j] = R[i][j];
#pragma unroll
    for (int i = 0; i < 3; ++i)
      out[144 + b*3 + i] = tv[i];
  }
}

extern "C" void kernel_launch(void* const* d_in, const int* in_sizes, int n_in,
                              void* d_out, int out_size, void* d_ws, size_t ws_size,
                              hipStream_t stream) {
  const float* srcE = (const float*)d_in[0];
  const float* tgtE = (const float*)d_in[1];
  const float* src  = (const float*)d_in[2];
  const float* tgt  = (const float*)d_in[3];
  float* out = (float*)d_out;

  // ws layout: [0,32KB) partials | Qp 2MB | Kp 2MB | Vp 512KB  (total ~4.53MB)
  float* part = (float*)d_ws;
  unsigned short* Qp = (unsigned short*)((char*)d_ws + 32768);
  unsigned short* Kp = (unsigned short*)((char*)d_ws + 32768 + (size_t)16*2048*32*2);
  float4* Vp = (float4*)((char*)d_ws + 32768 + (size_t)2*16*2048*32*2);

  hipLaunchKernelGGL(pack_kernel, dim3(256), dim3(128), 0, stream, srcE, tgtE, tgt, Qp, Kp, Vp);
  hipLaunchKernelGGL(corr_kernel, dim3(512), dim3(512), 0, stream, Qp, Kp, Vp, src, part);
  hipLaunchKernelGGL(finalize_kernel, dim3(1), dim3(1024), 0, stream, part, out);
}